// Round 1
// baseline (531.526 us; speedup 1.0000x reference)
//
#include <hip/hip_runtime.h>

typedef __bf16 bf16x8 __attribute__((ext_vector_type(8)));
typedef float f32x4 __attribute__((ext_vector_type(4)));

__device__ __forceinline__ unsigned short f2bf(float f) {
  union { float f; unsigned u; } v; v.f = f;
  unsigned r = v.u + 0x7fffu + ((v.u >> 16) & 1u);
  return (unsigned short)(r >> 16);
}

__device__ __forceinline__ void gl_lds16(const void* g, void* l) {
  __builtin_amdgcn_global_load_lds(
      (const __attribute__((address_space(1))) unsigned int*)g,
      (__attribute__((address_space(3))) unsigned int*)l, 16, 0, 0);
}

// ---------------- f32 -> bf16 convert (vectorized) ----------------
__global__ __launch_bounds__(256) void conv_bf16_kernel(
    const float* __restrict__ in, unsigned short* __restrict__ out, int n4) {
  int i = blockIdx.x * 256 + threadIdx.x;
  if (i < n4) {
    float4 v = ((const float4*)in)[i];
    union { unsigned short s[4]; unsigned long long u; } o;
    o.s[0] = f2bf(v.x); o.s[1] = f2bf(v.y); o.s[2] = f2bf(v.z); o.s[3] = f2bf(v.w);
    ((unsigned long long*)out)[i] = o.u;
  }
}

// ---------------- f32 [R][C] -> bf16 transposed [C][R] ----------------
__global__ __launch_bounds__(256) void tconv_kernel(
    const float* __restrict__ W, unsigned short* __restrict__ Wt, int R, int C) {
  __shared__ float t[32][33];
  int c0 = blockIdx.x * 32, r0 = blockIdx.y * 32;
  int tx = threadIdx.x, ty = threadIdx.y;
#pragma unroll
  for (int i = 0; i < 4; ++i)
    t[ty + i * 8][tx] = W[(size_t)(r0 + ty + i * 8) * C + c0 + tx];
  __syncthreads();
#pragma unroll
  for (int i = 0; i < 4; ++i)
    Wt[(size_t)(c0 + ty + i * 8) * R + r0 + tx] = f2bf(t[tx][ty + i * 8]);
}

// ---------------- bf16 GEMM: C[M,N] = A[M,K] * Bt[N,K]^T ----------------
// NORM: 0 none, 1 per-64-col RMSNorm all cols (q), 2 RMSNorm only cols<1024 (k)
// OUTF32: 1 -> float output, 0 -> bf16 output
template <int NORM, int OUTF32>
__global__ __launch_bounds__(256) void gemm_kernel(
    const unsigned short* __restrict__ A, const unsigned short* __restrict__ Bt,
    void* __restrict__ Cout, int M, int N, int K, const float* __restrict__ gamma) {
  __shared__ alignas(16) unsigned short Alds[128 * 32];
  __shared__ alignas(16) unsigned short Blds[128 * 32];
  const int tid = threadIdx.x;
  const int w = tid >> 6, l = tid & 63;
  const int lg = l & 15, lh = l >> 4;
  const int wr = w >> 1, wc = w & 1;
  const int brow = blockIdx.y * 128, bcol = blockIdx.x * 128;

  const f32x4 zero = {0.f, 0.f, 0.f, 0.f};
  f32x4 acc[4][4];
#pragma unroll
  for (int m = 0; m < 4; ++m)
#pragma unroll
    for (int n = 0; n < 4; ++n) acc[m][n] = zero;

  for (int k0 = 0; k0 < K; k0 += 32) {
    __syncthreads();
#pragma unroll
    for (int j = 0; j < 2; ++j) {
      int c = j * 256 + w * 64 + l;
      gl_lds16(A + (size_t)(brow + (c >> 2)) * K + k0 + (c & 3) * 8,
               (char*)Alds + (j * 256 + w * 64) * 16);
      gl_lds16(Bt + (size_t)(bcol + (c >> 2)) * K + k0 + (c & 3) * 8,
               (char*)Blds + (j * 256 + w * 64) * 16);
    }
    __syncthreads();
    bf16x8 af[4], bfr[4];
#pragma unroll
    for (int m = 0; m < 4; ++m)
      af[m] = *(const bf16x8*)(Alds + (wr * 64 + m * 16 + lg) * 32 + lh * 8);
#pragma unroll
    for (int n = 0; n < 4; ++n)
      bfr[n] = *(const bf16x8*)(Blds + (wc * 64 + n * 16 + lg) * 32 + lh * 8);
#pragma unroll
    for (int m = 0; m < 4; ++m)
#pragma unroll
      for (int n = 0; n < 4; ++n)
        acc[m][n] = __builtin_amdgcn_mfma_f32_16x16x32_bf16(af[m], bfr[n], acc[m][n], 0, 0, 0);
  }

  // fused per-head (64-col) RMSNorm: wave col-span == one head exactly
  if (NORM == 1 || (NORM == 2 && (bcol + wc * 64) < 1024)) {
    float gm[4];
#pragma unroll
    for (int n = 0; n < 4; ++n) gm[n] = gamma[n * 16 + lg];
#pragma unroll
    for (int m = 0; m < 4; ++m) {
#pragma unroll
      for (int i = 0; i < 4; ++i) {
        float ss = 0.f;
#pragma unroll
        for (int n = 0; n < 4; ++n) ss += acc[m][n][i] * acc[m][n][i];
        ss += __shfl_xor(ss, 1);
        ss += __shfl_xor(ss, 2);
        ss += __shfl_xor(ss, 4);
        ss += __shfl_xor(ss, 8);
        float inv = rsqrtf(ss * (1.0f / 64.0f) + 1e-6f);
#pragma unroll
        for (int n = 0; n < 4; ++n) acc[m][n][i] *= inv * gm[n];
      }
    }
  }

#pragma unroll
  for (int m = 0; m < 4; ++m)
#pragma unroll
    for (int n = 0; n < 4; ++n)
#pragma unroll
      for (int i = 0; i < 4; ++i) {
        size_t idx = (size_t)(brow + wr * 64 + m * 16 + lh * 4 + i) * N +
                     bcol + wc * 64 + n * 16 + lg;
        if (OUTF32) ((float*)Cout)[idx] = acc[m][n][i];
        else ((unsigned short*)Cout)[idx] = f2bf(acc[m][n][i]);
      }
}

// ---------------- flash attention: 1 block = (b, h, 128 q-rows) ----------------
__global__ __launch_bounds__(256) void flash_kernel(
    const unsigned short* __restrict__ Qb, const unsigned short* __restrict__ KVb,
    unsigned short* __restrict__ Ob) {
  const int L = 4096, Lc = 1024;
  const int qt = blockIdx.x, h = blockIdx.y, b = blockIdx.z;
  const int tid = threadIdx.x;
  const int w = tid >> 6, l = tid & 63, lg = l & 15, lh = l >> 4;
  __shared__ alignas(16) unsigned short Klds[64 * 72];   // [kv][d], pad->2-way
  __shared__ alignas(16) unsigned short Vtlds[64 * 72];  // [d][kv], pad
  __shared__ alignas(16) unsigned short Plds[4][32 * 72];

  const int qrow0 = b * L + qt * 128 + w * 32;
  bf16x8 qf[2][2];
#pragma unroll
  for (int mf = 0; mf < 2; ++mf)
#pragma unroll
    for (int dc = 0; dc < 2; ++dc)
      qf[mf][dc] = *(const bf16x8*)(Qb + (size_t)(qrow0 + mf * 16 + lg) * 1024 +
                                    h * 64 + dc * 32 + lh * 8);

  const f32x4 zero = {0.f, 0.f, 0.f, 0.f};
  f32x4 o[2][4];
  float mrun[2][4], lrun[2][4];
#pragma unroll
  for (int mf = 0; mf < 2; ++mf) {
#pragma unroll
    for (int nf = 0; nf < 4; ++nf) o[mf][nf] = zero;
#pragma unroll
    for (int i = 0; i < 4; ++i) { mrun[mf][i] = -1e30f; lrun[mf][i] = 0.f; }
  }

  for (int kt = 0; kt < 16; ++kt) {
    __syncthreads();
    // stage K [64][64] -> Klds[kv][d] (coalesced 16B chunks)
#pragma unroll
    for (int it = 0; it < 2; ++it) {
      int m = (tid >> 3) + it * 32;
      int d0 = (tid & 7) * 8;
      bf16x8 kv = *(const bf16x8*)(KVb + (size_t)(b * Lc + kt * 64 + m) * 2048 + h * 64 + d0);
      *(bf16x8*)(Klds + m * 72 + d0) = kv;
    }
    // stage V transposed -> Vtlds[d][kv]
#pragma unroll
    for (int it = 0; it < 2; ++it) {
      int d = tid & 63;
      int m0 = (tid >> 6) * 8 + it * 32;
      unsigned short tmp[8];
#pragma unroll
      for (int i = 0; i < 8; ++i)
        tmp[i] = KVb[(size_t)(b * Lc + kt * 64 + m0 + i) * 2048 + 1024 + h * 64 + d];
      *(bf16x8*)(Vtlds + d * 72 + m0) = *(bf16x8*)tmp;
    }
    __syncthreads();

    // S = Q K^T * 1/8
    bf16x8 kf[4][2];
#pragma unroll
    for (int nf = 0; nf < 4; ++nf)
#pragma unroll
      for (int dc = 0; dc < 2; ++dc)
        kf[nf][dc] = *(const bf16x8*)(Klds + (nf * 16 + lg) * 72 + dc * 32 + lh * 8);
    f32x4 s[2][4];
#pragma unroll
    for (int mf = 0; mf < 2; ++mf)
#pragma unroll
      for (int nf = 0; nf < 4; ++nf) {
        f32x4 t = zero;
#pragma unroll
        for (int dc = 0; dc < 2; ++dc)
          t = __builtin_amdgcn_mfma_f32_16x16x32_bf16(qf[mf][dc], kf[nf][dc], t, 0, 0, 0);
#pragma unroll
        for (int i = 0; i < 4; ++i) t[i] *= 0.125f;
        s[mf][nf] = t;
      }

    // online softmax (rows live in 16-lane groups)
#pragma unroll
    for (int mf = 0; mf < 2; ++mf) {
      float nm[4], r[4];
#pragma unroll
      for (int i = 0; i < 4; ++i) {
        float t = fmaxf(fmaxf(s[mf][0][i], s[mf][1][i]), fmaxf(s[mf][2][i], s[mf][3][i]));
        t = fmaxf(t, __shfl_xor(t, 1));
        t = fmaxf(t, __shfl_xor(t, 2));
        t = fmaxf(t, __shfl_xor(t, 4));
        t = fmaxf(t, __shfl_xor(t, 8));
        nm[i] = fmaxf(mrun[mf][i], t);
        r[i] = __expf(mrun[mf][i] - nm[i]);
        mrun[mf][i] = nm[i];
      }
#pragma unroll
      for (int i = 0; i < 4; ++i) {
        float rs = 0.f;
#pragma unroll
        for (int nf = 0; nf < 4; ++nf) {
          float p = __expf(s[mf][nf][i] - nm[i]);
          s[mf][nf][i] = p;
          rs += p;
        }
        rs += __shfl_xor(rs, 1);
        rs += __shfl_xor(rs, 2);
        rs += __shfl_xor(rs, 4);
        rs += __shfl_xor(rs, 8);
        lrun[mf][i] = lrun[mf][i] * r[i] + rs;
#pragma unroll
        for (int nf = 0; nf < 4; ++nf) o[mf][nf][i] *= r[i];
      }
      // P (C-layout) -> per-wave LDS for A-fragment re-layout
#pragma unroll
      for (int nf = 0; nf < 4; ++nf)
#pragma unroll
        for (int i = 0; i < 4; ++i)
          Plds[w][(mf * 16 + lh * 4 + i) * 72 + nf * 16 + lg] = f2bf(s[mf][nf][i]);
    }

    // O += P V
    bf16x8 pf[2][2], vf[4][2];
#pragma unroll
    for (int mf = 0; mf < 2; ++mf)
#pragma unroll
      for (int kc = 0; kc < 2; ++kc)
        pf[mf][kc] = *(const bf16x8*)(Plds[w] + (mf * 16 + lg) * 72 + kc * 32 + lh * 8);
#pragma unroll
    for (int nf = 0; nf < 4; ++nf)
#pragma unroll
      for (int kc = 0; kc < 2; ++kc)
        vf[nf][kc] = *(const bf16x8*)(Vtlds + (nf * 16 + lg) * 72 + kc * 32 + lh * 8);
#pragma unroll
    for (int mf = 0; mf < 2; ++mf)
#pragma unroll
      for (int nf = 0; nf < 4; ++nf)
#pragma unroll
        for (int kc = 0; kc < 2; ++kc)
          o[mf][nf] = __builtin_amdgcn_mfma_f32_16x16x32_bf16(pf[mf][kc], vf[nf][kc], o[mf][nf], 0, 0, 0);
  }

  // normalize + store bf16
#pragma unroll
  for (int mf = 0; mf < 2; ++mf) {
    float inv[4];
#pragma unroll
    for (int i = 0; i < 4; ++i) inv[i] = 1.f / lrun[mf][i];
#pragma unroll
    for (int nf = 0; nf < 4; ++nf)
#pragma unroll
      for (int i = 0; i < 4; ++i)
        Ob[(size_t)(qrow0 + mf * 16 + lh * 4 + i) * 1024 + h * 64 + nf * 16 + lg] =
            f2bf(o[mf][nf][i] * inv[i]);
  }
}

extern "C" void kernel_launch(void* const* d_in, const int* in_sizes, int n_in,
                              void* d_out, int out_size, void* d_ws, size_t ws_size,
                              hipStream_t stream) {
  const float* x     = (const float*)d_in[0];
  const float* ctx   = (const float*)d_in[1];
  const float* Wq    = (const float*)d_in[2];
  const float* Wkv   = (const float*)d_in[3];
  const float* Wproj = (const float*)d_in[4];
  const float* qg    = (const float*)d_in[5];
  const float* kg    = (const float*)d_in[6];
  float* out = (float*)d_out;

  // B=4 L=4096 Lc=1024 D=1024 CTX=1024 H=16 hd=64
  char* ws = (char*)d_ws;
  unsigned short* xb   = (unsigned short*)(ws);                        // 32MB [16384,1024]; reused as Ob
  unsigned short* cb   = (unsigned short*)(ws + (size_t)32 * 1048576); // 8MB  [4096,1024]
  unsigned short* Wqt  = (unsigned short*)(ws + (size_t)40 * 1048576); // 2MB  [1024,1024]
  unsigned short* Wkvt = (unsigned short*)(ws + (size_t)42 * 1048576); // 4MB  [2048,1024]
  unsigned short* Wpt  = (unsigned short*)(ws + (size_t)46 * 1048576); // 2MB  [1024,1024]
  unsigned short* Qb   = (unsigned short*)(ws + (size_t)48 * 1048576); // 32MB [16384,1024]
  unsigned short* KVb  = (unsigned short*)(ws + (size_t)80 * 1048576); // 16MB [4096,2048]
  unsigned short* Ob   = xb;

  conv_bf16_kernel<<<16384, 256, 0, stream>>>(x, xb, 4194304);
  conv_bf16_kernel<<<4096, 256, 0, stream>>>(ctx, cb, 1048576);
  tconv_kernel<<<dim3(32, 32), dim3(32, 8), 0, stream>>>(Wq, Wqt, 1024, 1024);
  tconv_kernel<<<dim3(64, 32), dim3(32, 8), 0, stream>>>(Wkv, Wkvt, 1024, 2048);
  tconv_kernel<<<dim3(32, 32), dim3(32, 8), 0, stream>>>(Wproj, Wpt, 1024, 1024);

  // Q = x Wq (+q RMSNorm fused), bf16
  gemm_kernel<1, 0><<<dim3(8, 128), 256, 0, stream>>>(xb, Wqt, Qb, 16384, 1024, 1024, qg);
  // KV = ctx Wkv (+k RMSNorm fused on cols<1024), bf16
  gemm_kernel<2, 0><<<dim3(16, 32), 256, 0, stream>>>(cb, Wkvt, KVb, 4096, 2048, 1024, kg);
  // attention
  flash_kernel<<<dim3(32, 16, 4), 256, 0, stream>>>(Qb, KVb, Ob);
  // out = O Wproj, f32
  gemm_kernel<0, 1><<<dim3(8, 128), 256, 0, stream>>>(Ob, Wpt, out, 16384, 1024, 1024, nullptr);
}

// Round 2
// 440.981 us; speedup vs baseline: 1.2053x; 1.2053x over previous
//
#include <hip/hip_runtime.h>

typedef __bf16 bf16x8 __attribute__((ext_vector_type(8)));
typedef float f32x4 __attribute__((ext_vector_type(4)));
typedef unsigned short ushort_t;

__device__ __forceinline__ unsigned short f2bf(float f) {
  union { float f; unsigned u; } v; v.f = f;
  unsigned r = v.u + 0x7fffu + ((v.u >> 16) & 1u);
  return (unsigned short)(r >> 16);
}

__device__ __forceinline__ void gl_lds16(const void* g, void* l) {
  __builtin_amdgcn_global_load_lds(
      (const __attribute__((address_space(1))) unsigned int*)g,
      (__attribute__((address_space(3))) unsigned int*)l, 16, 0, 0);
}

// ---------------- f32 -> bf16 convert (vectorized) ----------------
__global__ __launch_bounds__(256) void conv_bf16_kernel(
    const float* __restrict__ in, unsigned short* __restrict__ out, int n4) {
  int i = blockIdx.x * 256 + threadIdx.x;
  if (i < n4) {
    float4 v = ((const float4*)in)[i];
    union { unsigned short s[4]; unsigned long long u; } o;
    o.s[0] = f2bf(v.x); o.s[1] = f2bf(v.y); o.s[2] = f2bf(v.z); o.s[3] = f2bf(v.w);
    ((unsigned long long*)out)[i] = o.u;
  }
}

// ---------------- f32 [R][C] -> bf16 transposed [C][R] ----------------
__global__ __launch_bounds__(256) void tconv_kernel(
    const float* __restrict__ W, unsigned short* __restrict__ Wt, int R, int C) {
  __shared__ float t[32][33];
  int c0 = blockIdx.x * 32, r0 = blockIdx.y * 32;
  int tx = threadIdx.x, ty = threadIdx.y;
#pragma unroll
  for (int i = 0; i < 4; ++i)
    t[ty + i * 8][tx] = W[(size_t)(r0 + ty + i * 8) * C + c0 + tx];
  __syncthreads();
#pragma unroll
  for (int i = 0; i < 4; ++i)
    Wt[(size_t)(c0 + ty + i * 8) * R + r0 + tx] = f2bf(t[tx][ty + i * 8]);
}

// ---------------- V transpose: KVb[b,kv,1024+h*64+d] -> Vt[b,h,d,kv] ----------------
__global__ __launch_bounds__(256) void vtrans_kernel(
    const unsigned short* __restrict__ KVb, unsigned short* __restrict__ Vt) {
  const int kt = blockIdx.x, h = blockIdx.y, b = blockIdx.z;
  const int tid = threadIdx.x;
#pragma unroll
  for (int it = 0; it < 2; ++it) {
    int d = (tid >> 3) + it * 32;
    int kv0 = (tid & 7) * 8;
    unsigned short tmp[8];
#pragma unroll
    for (int j = 0; j < 8; ++j)
      tmp[j] = KVb[(size_t)(b * 1024 + kt * 64 + kv0 + j) * 2048 + 1024 + h * 64 + d];
    *(bf16x8*)(Vt + ((size_t)((b * 16 + h) * 64) + d) * 1024 + kt * 64 + kv0) =
        *(bf16x8*)tmp;
  }
}

// ---------------- bf16 GEMM (2-phase dbuf): C[M,N] = A[M,K] * Bt[N,K]^T ----------------
template <int NORM, int OUTF32>
__global__ __launch_bounds__(256) void gemm_kernel(
    const unsigned short* __restrict__ A, const unsigned short* __restrict__ Bt,
    void* __restrict__ Cout, int M, int N, int K, const float* __restrict__ gamma) {
  __shared__ alignas(16) unsigned short Alds[2][128 * 32];
  __shared__ alignas(16) unsigned short Blds[2][128 * 32];
  const int tid = threadIdx.x;
  const int w = tid >> 6, l = tid & 63;
  const int lg = l & 15, lh = l >> 4;
  const int wr = w >> 1, wc = w & 1;
  const int brow = blockIdx.y * 128, bcol = blockIdx.x * 128;

  const f32x4 zero = {0.f, 0.f, 0.f, 0.f};
  f32x4 acc[4][4];
#pragma unroll
  for (int m = 0; m < 4; ++m)
#pragma unroll
    for (int n = 0; n < 4; ++n) acc[m][n] = zero;

  auto STAGE = [&](int buf, int k0) {
#pragma unroll
    for (int j = 0; j < 2; ++j) {
      int c = j * 256 + w * 64 + l;
      gl_lds16(A + (size_t)(brow + (c >> 2)) * K + k0 + (c & 3) * 8,
               (char*)Alds[buf] + (j * 256 + w * 64) * 16);
      gl_lds16(Bt + (size_t)(bcol + (c >> 2)) * K + k0 + (c & 3) * 8,
               (char*)Blds[buf] + (j * 256 + w * 64) * 16);
    }
  };

  STAGE(0, 0);
  __syncthreads();
  for (int k0 = 0; k0 < K; k0 += 32) {
    int cur = (k0 >> 5) & 1;
    if (k0 + 32 < K) STAGE(cur ^ 1, k0 + 32);
    bf16x8 af[4], bfr[4];
#pragma unroll
    for (int m = 0; m < 4; ++m)
      af[m] = *(const bf16x8*)(Alds[cur] + (wr * 64 + m * 16 + lg) * 32 + lh * 8);
#pragma unroll
    for (int n = 0; n < 4; ++n)
      bfr[n] = *(const bf16x8*)(Blds[cur] + (wc * 64 + n * 16 + lg) * 32 + lh * 8);
#pragma unroll
    for (int m = 0; m < 4; ++m)
#pragma unroll
      for (int n = 0; n < 4; ++n)
        acc[m][n] = __builtin_amdgcn_mfma_f32_16x16x32_bf16(af[m], bfr[n], acc[m][n], 0, 0, 0);
    __syncthreads();
  }

  if (NORM == 1 || (NORM == 2 && (bcol + wc * 64) < 1024)) {
    float gm[4];
#pragma unroll
    for (int n = 0; n < 4; ++n) gm[n] = gamma[n * 16 + lg];
#pragma unroll
    for (int m = 0; m < 4; ++m) {
#pragma unroll
      for (int i = 0; i < 4; ++i) {
        float ss = 0.f;
#pragma unroll
        for (int n = 0; n < 4; ++n) ss += acc[m][n][i] * acc[m][n][i];
        ss += __shfl_xor(ss, 1);
        ss += __shfl_xor(ss, 2);
        ss += __shfl_xor(ss, 4);
        ss += __shfl_xor(ss, 8);
        float inv = rsqrtf(ss * (1.0f / 64.0f) + 1e-6f);
#pragma unroll
        for (int n = 0; n < 4; ++n) acc[m][n][i] *= inv * gm[n];
      }
    }
  }

#pragma unroll
  for (int m = 0; m < 4; ++m)
#pragma unroll
    for (int n = 0; n < 4; ++n)
#pragma unroll
      for (int i = 0; i < 4; ++i) {
        size_t idx = (size_t)(brow + wr * 64 + m * 16 + lh * 4 + i) * N +
                     bcol + wc * 64 + n * 16 + lg;
        if (OUTF32) ((float*)Cout)[idx] = acc[m][n][i];
        else ((unsigned short*)Cout)[idx] = f2bf(acc[m][n][i]);
      }
}

// ---------------- flash attention v2: gl_lds staging + swizzle + 2-phase dbuf ----------------
__global__ __launch_bounds__(256) void flash_kernel(
    const unsigned short* __restrict__ Qb, const unsigned short* __restrict__ KVb,
    const unsigned short* __restrict__ Vt, unsigned short* __restrict__ Ob) {
  const int qt = blockIdx.x, h = blockIdx.y, b = blockIdx.z;
  const int tid = threadIdx.x;
  const int w = tid >> 6, l = tid & 63, lg = l & 15, lh = l >> 4;
  __shared__ alignas(16) char Kl[2][8192];   // [kv 64][d 64] bf16, XOR-swizzled
  __shared__ alignas(16) char Vl[2][8192];   // [d 64][kv 64] bf16, XOR-swizzled
  __shared__ alignas(16) unsigned short Pl[4][32 * 72];

  const int qrow0 = b * 4096 + qt * 128 + w * 32;
  bf16x8 qf[2][2];
#pragma unroll
  for (int mf = 0; mf < 2; ++mf)
#pragma unroll
    for (int dc = 0; dc < 2; ++dc)
      qf[mf][dc] = *(const bf16x8*)(Qb + (size_t)(qrow0 + mf * 16 + lg) * 1024 +
                                    h * 64 + dc * 32 + lh * 8);

  const char* Kg = (const char*)KVb + (size_t)b * 1024 * 4096 + h * 128;  // row stride 4096B
  const char* Vg = (const char*)Vt + (size_t)(b * 16 + h) * 64 * 2048;    // row stride 2048B

  auto STAGE = [&](int buf, int kt) {
#pragma unroll
    for (int c = 0; c < 2; ++c) {
      int o = (c * 256 + tid) * 16;                // per-lane LDS byte offset in tile
      int op = o ^ (((o >> 7) & 7) << 4);          // pre-swizzled source offset
      int row = op >> 7, cb = op & 127;
      gl_lds16(Kg + (size_t)(kt * 64 + row) * 4096 + cb, Kl[buf] + (c * 256 + w * 64) * 16);
      gl_lds16(Vg + (size_t)row * 2048 + kt * 128 + cb, Vl[buf] + (c * 256 + w * 64) * 16);
    }
  };

  const f32x4 zero = {0.f, 0.f, 0.f, 0.f};
  f32x4 o_[2][4];
  float mr[2][4], lr[2][4];
#pragma unroll
  for (int mf = 0; mf < 2; ++mf) {
#pragma unroll
    for (int nf = 0; nf < 4; ++nf) o_[mf][nf] = zero;
#pragma unroll
    for (int i = 0; i < 4; ++i) { mr[mf][i] = -1e30f; lr[mf][i] = 0.f; }
  }

  const float C = 0.18033688f;  // log2(e) / sqrt(64)

  STAGE(0, 0);
  __syncthreads();
  for (int kt = 0; kt < 16; ++kt) {
    const int cur = kt & 1;
    if (kt < 15) STAGE(cur ^ 1, kt + 1);

    // S = Q K^T (raw; scale folded into exp2)
    bf16x8 kf[4][2];
#pragma unroll
    for (int nf = 0; nf < 4; ++nf)
#pragma unroll
      for (int dc = 0; dc < 2; ++dc) {
        int r = nf * 16 + lg;
        int byte_ = (r * 128 + dc * 64 + lh * 16) ^ ((r & 7) << 4);
        kf[nf][dc] = *(const bf16x8*)(Kl[cur] + byte_);
      }
    f32x4 s[2][4];
#pragma unroll
    for (int mf = 0; mf < 2; ++mf)
#pragma unroll
      for (int nf = 0; nf < 4; ++nf) {
        f32x4 t = zero;
#pragma unroll
        for (int dc = 0; dc < 2; ++dc)
          t = __builtin_amdgcn_mfma_f32_16x16x32_bf16(qf[mf][dc], kf[nf][dc], t, 0, 0, 0);
        s[mf][nf] = t;
      }

    // online softmax
#pragma unroll
    for (int mf = 0; mf < 2; ++mf) {
      float nm[4], r[4];
#pragma unroll
      for (int i = 0; i < 4; ++i) {
        float t = fmaxf(fmaxf(s[mf][0][i], s[mf][1][i]), fmaxf(s[mf][2][i], s[mf][3][i]));
        t = fmaxf(t, __shfl_xor(t, 1));
        t = fmaxf(t, __shfl_xor(t, 2));
        t = fmaxf(t, __shfl_xor(t, 4));
        t = fmaxf(t, __shfl_xor(t, 8));
        nm[i] = fmaxf(mr[mf][i], t);
        r[i] = exp2f((mr[mf][i] - nm[i]) * C);
        mr[mf][i] = nm[i];
      }
#pragma unroll
      for (int i = 0; i < 4; ++i) {
        float rs = 0.f;
#pragma unroll
        for (int nf = 0; nf < 4; ++nf) {
          float p = exp2f((s[mf][nf][i] - nm[i]) * C);
          s[mf][nf][i] = p;
          rs += p;
        }
        rs += __shfl_xor(rs, 1);
        rs += __shfl_xor(rs, 2);
        rs += __shfl_xor(rs, 4);
        rs += __shfl_xor(rs, 8);
        lr[mf][i] = lr[mf][i] * r[i] + rs;
#pragma unroll
        for (int nf = 0; nf < 4; ++nf) o_[mf][nf][i] *= r[i];
      }
#pragma unroll
      for (int nf = 0; nf < 4; ++nf)
#pragma unroll
        for (int i = 0; i < 4; ++i)
          Pl[w][(mf * 16 + lh * 4 + i) * 72 + nf * 16 + lg] = f2bf(s[mf][nf][i]);
    }

    // O += P V  (V B-frags from swizzled Vt tile)
    bf16x8 pf[2][2], vf[4][2];
#pragma unroll
    for (int mf = 0; mf < 2; ++mf)
#pragma unroll
      for (int kc = 0; kc < 2; ++kc)
        pf[mf][kc] = *(const bf16x8*)(Pl[w] + (mf * 16 + lg) * 72 + kc * 32 + lh * 8);
#pragma unroll
    for (int nf = 0; nf < 4; ++nf)
#pragma unroll
      for (int kc = 0; kc < 2; ++kc) {
        int r = nf * 16 + lg;
        int byte_ = (r * 128 + kc * 64 + lh * 16) ^ ((r & 7) << 4);
        vf[nf][kc] = *(const bf16x8*)(Vl[cur] + byte_);
      }
#pragma unroll
    for (int mf = 0; mf < 2; ++mf)
#pragma unroll
      for (int nf = 0; nf < 4; ++nf)
#pragma unroll
        for (int kc = 0; kc < 2; ++kc)
          o_[mf][nf] = __builtin_amdgcn_mfma_f32_16x16x32_bf16(pf[mf][kc], vf[nf][kc], o_[mf][nf], 0, 0, 0);

    __syncthreads();
  }

#pragma unroll
  for (int mf = 0; mf < 2; ++mf) {
    float inv[4];
#pragma unroll
    for (int i = 0; i < 4; ++i) inv[i] = 1.f / lr[mf][i];
#pragma unroll
    for (int nf = 0; nf < 4; ++nf)
#pragma unroll
      for (int i = 0; i < 4; ++i)
        Ob[(size_t)(qrow0 + mf * 16 + lh * 4 + i) * 1024 + h * 64 + nf * 16 + lg] =
            f2bf(o_[mf][nf][i] * inv[i]);
  }
}

extern "C" void kernel_launch(void* const* d_in, const int* in_sizes, int n_in,
                              void* d_out, int out_size, void* d_ws, size_t ws_size,
                              hipStream_t stream) {
  const float* x     = (const float*)d_in[0];
  const float* ctx   = (const float*)d_in[1];
  const float* Wq    = (const float*)d_in[2];
  const float* Wkv   = (const float*)d_in[3];
  const float* Wproj = (const float*)d_in[4];
  const float* qg    = (const float*)d_in[5];
  const float* kg    = (const float*)d_in[6];
  float* out = (float*)d_out;

  // B=4 L=4096 Lc=1024 D=1024 CTX=1024 H=16 hd=64
  char* ws = (char*)d_ws;
  unsigned short* xb   = (unsigned short*)(ws);                        // 32MB; reused as Ob
  unsigned short* cb   = (unsigned short*)(ws + (size_t)32 * 1048576); // 8MB; reused as Vt
  unsigned short* Wqt  = (unsigned short*)(ws + (size_t)40 * 1048576); // 2MB
  unsigned short* Wkvt = (unsigned short*)(ws + (size_t)42 * 1048576); // 4MB
  unsigned short* Wpt  = (unsigned short*)(ws + (size_t)46 * 1048576); // 2MB
  unsigned short* Qb   = (unsigned short*)(ws + (size_t)48 * 1048576); // 32MB
  unsigned short* KVb  = (unsigned short*)(ws + (size_t)80 * 1048576); // 16MB
  unsigned short* Vt   = cb;  // cb is dead after the KV GEMM
  unsigned short* Ob   = xb;  // xb is dead after the Q GEMM

  conv_bf16_kernel<<<16384, 256, 0, stream>>>(x, xb, 4194304);
  conv_bf16_kernel<<<4096, 256, 0, stream>>>(ctx, cb, 1048576);
  tconv_kernel<<<dim3(32, 32), dim3(32, 8), 0, stream>>>(Wq, Wqt, 1024, 1024);
  tconv_kernel<<<dim3(64, 32), dim3(32, 8), 0, stream>>>(Wkv, Wkvt, 1024, 2048);
  tconv_kernel<<<dim3(32, 32), dim3(32, 8), 0, stream>>>(Wproj, Wpt, 1024, 1024);

  gemm_kernel<1, 0><<<dim3(8, 128), 256, 0, stream>>>(xb, Wqt, Qb, 16384, 1024, 1024, qg);
  gemm_kernel<2, 0><<<dim3(16, 32), 256, 0, stream>>>(cb, Wkvt, KVb, 4096, 2048, 1024, kg);
  vtrans_kernel<<<dim3(16, 16, 4), 256, 0, stream>>>(KVb, Vt);
  flash_kernel<<<dim3(32, 16, 4), 256, 0, stream>>>(Qb, KVb, Vt, Ob);
  gemm_kernel<0, 1><<<dim3(8, 128), 256, 0, stream>>>(Ob, Wpt, out, 16384, 1024, 1024, nullptr);
}

// Round 4
// 357.663 us; speedup vs baseline: 1.4861x; 1.2330x over previous
//
#include <hip/hip_runtime.h>

typedef __bf16 bf16x8 __attribute__((ext_vector_type(8)));
typedef float f32x4 __attribute__((ext_vector_type(4)));
typedef short s16x4 __attribute__((ext_vector_type(4)));

__device__ __forceinline__ unsigned short f2bf(float f) {
  union { float f; unsigned u; } v; v.f = f;
  unsigned r = v.u + 0x7fffu + ((v.u >> 16) & 1u);
  return (unsigned short)(r >> 16);
}

__device__ __forceinline__ unsigned pack_bf16(float lo, float hi) {
  return (unsigned)f2bf(lo) | ((unsigned)f2bf(hi) << 16);
}

__device__ __forceinline__ void gl_lds16(const void* g, void* l) {
  __builtin_amdgcn_global_load_lds(
      (const __attribute__((address_space(1))) unsigned int*)g,
      (__attribute__((address_space(3))) unsigned int*)l, 16, 0, 0);
}

// ---------------- f32 -> bf16 convert (vectorized) ----------------
__global__ __launch_bounds__(256) void conv_bf16_kernel(
    const float* __restrict__ in, unsigned short* __restrict__ out, int n4) {
  int i = blockIdx.x * 256 + threadIdx.x;
  if (i < n4) {
    float4 v = ((const float4*)in)[i];
    union { unsigned short s[4]; unsigned long long u; } o;
    o.s[0] = f2bf(v.x); o.s[1] = f2bf(v.y); o.s[2] = f2bf(v.z); o.s[3] = f2bf(v.w);
    ((unsigned long long*)out)[i] = o.u;
  }
}

// ---------------- f32 [R][C] -> bf16 transposed [C][R] ----------------
__global__ __launch_bounds__(256) void tconv_kernel(
    const float* __restrict__ W, unsigned short* __restrict__ Wt, int R, int C) {
  __shared__ float t[32][33];
  int c0 = blockIdx.x * 32, r0 = blockIdx.y * 32;
  int tx = threadIdx.x, ty = threadIdx.y;
#pragma unroll
  for (int i = 0; i < 4; ++i)
    t[ty + i * 8][tx] = W[(size_t)(r0 + ty + i * 8) * C + c0 + tx];
  __syncthreads();
#pragma unroll
  for (int i = 0; i < 4; ++i)
    Wt[(size_t)(c0 + ty + i * 8) * R + r0 + tx] = f2bf(t[tx][ty + i * 8]);
}

// ---------------- V transpose: KVb[b,kv,1024+h*64+d] -> Vt[b,h,d,kv] ----------------
__global__ __launch_bounds__(256) void vtrans_kernel(
    const unsigned short* __restrict__ KVb, unsigned short* __restrict__ Vt) {
  const int kt = blockIdx.x, h = blockIdx.y, b = blockIdx.z;
  const int tid = threadIdx.x;
#pragma unroll
  for (int it = 0; it < 2; ++it) {
    int d = (tid >> 3) + it * 32;
    int kv0 = (tid & 7) * 8;
    unsigned short tmp[8];
#pragma unroll
    for (int j = 0; j < 8; ++j)
      tmp[j] = KVb[(size_t)(b * 1024 + kt * 64 + kv0 + j) * 2048 + 1024 + h * 64 + d];
    *(bf16x8*)(Vt + ((size_t)((b * 16 + h) * 64) + d) * 1024 + kt * 64 + kv0) =
        *(bf16x8*)tmp;
  }
}

// ---------------- bf16 GEMM (2-phase dbuf): C[M,N] = A[M,K] * Bt[N,K]^T ----------------
template <int NORM, int OUTF32>
__global__ __launch_bounds__(256) void gemm_kernel(
    const unsigned short* __restrict__ A, const unsigned short* __restrict__ Bt,
    void* __restrict__ Cout, int M, int N, int K, const float* __restrict__ gamma) {
  __shared__ alignas(16) unsigned short Alds[2][128 * 32];
  __shared__ alignas(16) unsigned short Blds[2][128 * 32];
  const int tid = threadIdx.x;
  const int w = tid >> 6, l = tid & 63;
  const int lg = l & 15, lh = l >> 4;
  const int wr = w >> 1, wc = w & 1;
  const int brow = blockIdx.y * 128, bcol = blockIdx.x * 128;

  const f32x4 zero = {0.f, 0.f, 0.f, 0.f};
  f32x4 acc[4][4];
#pragma unroll
  for (int m = 0; m < 4; ++m)
#pragma unroll
    for (int n = 0; n < 4; ++n) acc[m][n] = zero;

  auto STAGE = [&](int buf, int k0) {
#pragma unroll
    for (int j = 0; j < 2; ++j) {
      int c = j * 256 + w * 64 + l;
      gl_lds16(A + (size_t)(brow + (c >> 2)) * K + k0 + (c & 3) * 8,
               (char*)Alds[buf] + (j * 256 + w * 64) * 16);
      gl_lds16(Bt + (size_t)(bcol + (c >> 2)) * K + k0 + (c & 3) * 8,
               (char*)Blds[buf] + (j * 256 + w * 64) * 16);
    }
  };

  STAGE(0, 0);
  __syncthreads();
  for (int k0 = 0; k0 < K; k0 += 32) {
    int cur = (k0 >> 5) & 1;
    if (k0 + 32 < K) STAGE(cur ^ 1, k0 + 32);
    bf16x8 af[4], bfr[4];
#pragma unroll
    for (int m = 0; m < 4; ++m)
      af[m] = *(const bf16x8*)(Alds[cur] + (wr * 64 + m * 16 + lg) * 32 + lh * 8);
#pragma unroll
    for (int n = 0; n < 4; ++n)
      bfr[n] = *(const bf16x8*)(Blds[cur] + (wc * 64 + n * 16 + lg) * 32 + lh * 8);
#pragma unroll
    for (int m = 0; m < 4; ++m)
#pragma unroll
      for (int n = 0; n < 4; ++n)
        acc[m][n] = __builtin_amdgcn_mfma_f32_16x16x32_bf16(af[m], bfr[n], acc[m][n], 0, 0, 0);
    __syncthreads();
  }

  if (NORM == 1 || (NORM == 2 && (bcol + wc * 64) < 1024)) {
    float gm[4];
#pragma unroll
    for (int n = 0; n < 4; ++n) gm[n] = gamma[n * 16 + lg];
#pragma unroll
    for (int m = 0; m < 4; ++m) {
#pragma unroll
      for (int i = 0; i < 4; ++i) {
        float ss = 0.f;
#pragma unroll
        for (int n = 0; n < 4; ++n) ss += acc[m][n][i] * acc[m][n][i];
        ss += __shfl_xor(ss, 1);
        ss += __shfl_xor(ss, 2);
        ss += __shfl_xor(ss, 4);
        ss += __shfl_xor(ss, 8);
        float inv = rsqrtf(ss * (1.0f / 64.0f) + 1e-6f);
#pragma unroll
        for (int n = 0; n < 4; ++n) acc[m][n][i] *= inv * gm[n];
      }
    }
  }

#pragma unroll
  for (int m = 0; m < 4; ++m)
#pragma unroll
    for (int n = 0; n < 4; ++n)
#pragma unroll
      for (int i = 0; i < 4; ++i) {
        size_t idx = (size_t)(brow + wr * 64 + m * 16 + lh * 4 + i) * N +
                     bcol + wc * 64 + n * 16 + lg;
        if (OUTF32) ((float*)Cout)[idx] = acc[m][n][i];
        else ((unsigned short*)Cout)[idx] = f2bf(acc[m][n][i]);
      }
}

// ---------------- flash attention v4: swapped QK^T, in-register P, no inline asm ----------------
// Per block: 128 q-rows of one (b,h); per wave: 32 q-rows. KVBLK=64, dbuf LDS.
__global__ __launch_bounds__(256) void flash_kernel(
    const unsigned short* __restrict__ Qb, const unsigned short* __restrict__ KVb,
    const unsigned short* __restrict__ Vt, unsigned short* __restrict__ Ob) {
  // XCD-aware bijective swizzle: 2048 blocks, 8 XCDs, 256 per XCD.
  const int orig = blockIdx.x;
  const int wgid = (orig & 7) * 256 + (orig >> 3);
  const int qt = wgid & 31, h = (wgid >> 5) & 15, b = wgid >> 9;
  const int tid = threadIdx.x;
  const int w = tid >> 6, l = tid & 63, lg = l & 15, lh = l >> 4;
  __shared__ alignas(16) char Kl[2][8192];   // [kv 64][d 64] bf16, XOR-swizzled
  __shared__ alignas(16) char Vl[2][8192];   // [d 64][kv 64] bf16, XOR-swizzled

  const int qrow0 = b * 4096 + qt * 128 + w * 32;
  // Q as B-fragments of S^T = K Q^T : col q = mff*16+lg, k = d = dc*32+lh*8
  bf16x8 qfr[2][2];
#pragma unroll
  for (int mff = 0; mff < 2; ++mff)
#pragma unroll
    for (int dc = 0; dc < 2; ++dc)
      qfr[mff][dc] = *(const bf16x8*)(Qb + (size_t)(qrow0 + mff * 16 + lg) * 1024 +
                                      h * 64 + dc * 32 + lh * 8);

  const char* Kg = (const char*)KVb + (size_t)b * 1024 * 4096 + h * 128;  // row stride 4096B
  const char* Vg = (const char*)Vt + (size_t)(b * 16 + h) * 64 * 2048;    // row stride 2048B

  auto STAGE = [&](int buf, int kt) {
#pragma unroll
    for (int c = 0; c < 2; ++c) {
      int o = (c * 256 + tid) * 16;                // per-lane LDS byte offset in tile
      int op = o ^ (((o >> 7) & 7) << 4);          // pre-swizzled source offset
      int row = op >> 7, cb = op & 127;
      gl_lds16(Kg + (size_t)(kt * 64 + row) * 4096 + cb, Kl[buf] + (c * 256 + w * 64) * 16);
      gl_lds16(Vg + (size_t)row * 2048 + kt * 128 + cb, Vl[buf] + (c * 256 + w * 64) * 16);
    }
  };

  const f32x4 zero = {0.f, 0.f, 0.f, 0.f};
  f32x4 o_[4][2];   // [df][qf] : O^T frag, row d = df*16+lh*4+i, col q = qf*16+lg
  float m_[2], l_[2];
#pragma unroll
  for (int df = 0; df < 4; ++df)
#pragma unroll
    for (int qf = 0; qf < 2; ++qf) o_[df][qf] = zero;
  m_[0] = m_[1] = -1e30f;
  l_[0] = l_[1] = 0.f;

  const float C = 0.18033688f;   // log2(e)/sqrt(64)

  STAGE(0, 0);
  __syncthreads();
  for (int kt = 0; kt < 16; ++kt) {
    const int cur = kt & 1;
    if (kt < 15) STAGE(cur ^ 1, kt + 1);

    // S^T[kv][q] : A = K rows (kv), B = Q cols (q)
    f32x4 st[4][2];
#pragma unroll
    for (int kvf = 0; kvf < 4; ++kvf)
#pragma unroll
      for (int mff = 0; mff < 2; ++mff) st[kvf][mff] = zero;
#pragma unroll
    for (int dc = 0; dc < 2; ++dc)
#pragma unroll
      for (int kvf = 0; kvf < 4; ++kvf) {
        int r = kvf * 16 + lg;
        int byte_ = (r * 128 + dc * 64 + lh * 16) ^ ((r & 7) << 4);
        bf16x8 kf = *(const bf16x8*)(Kl[cur] + byte_);
#pragma unroll
        for (int mff = 0; mff < 2; ++mff)
          st[kvf][mff] = __builtin_amdgcn_mfma_f32_16x16x32_bf16(kf, qfr[mff][dc], st[kvf][mff], 0, 0, 0);
      }

    // row-max per q (16 lane-local, then xor16/32 across lh groups)
    float pmax[2];
#pragma unroll
    for (int qf = 0; qf < 2; ++qf) {
      float t = st[0][qf][0];
#pragma unroll
      for (int kvf = 0; kvf < 4; ++kvf)
#pragma unroll
        for (int i = 0; i < 4; ++i) t = fmaxf(t, st[kvf][qf][i]);
      t = fmaxf(t, __shfl_xor(t, 16));
      t = fmaxf(t, __shfl_xor(t, 32));
      pmax[qf] = t;
    }

    // online-softmax rescale every tile
#pragma unroll
    for (int qf = 0; qf < 2; ++qf) {
      float nm = fmaxf(m_[qf], pmax[qf]);
      float r = exp2f((m_[qf] - nm) * C);
      m_[qf] = nm;
      l_[qf] *= r;
#pragma unroll
      for (int df = 0; df < 4; ++df)
#pragma unroll
        for (int i = 0; i < 4; ++i) o_[df][qf][i] *= r;
    }

    // P = exp2((s-m)*C), row-sum, pack to bf16 B-fragments (plain-C pack)
    unsigned pw[4][2][2];
#pragma unroll
    for (int qf = 0; qf < 2; ++qf) {
      float rs = 0.f;
#pragma unroll
      for (int kvf = 0; kvf < 4; ++kvf) {
#pragma unroll
        for (int i = 0; i < 4; ++i) {
          float p = exp2f((st[kvf][qf][i] - m_[qf]) * C);
          st[kvf][qf][i] = p;
          rs += p;
        }
        pw[kvf][qf][0] = pack_bf16(st[kvf][qf][0], st[kvf][qf][1]);
        pw[kvf][qf][1] = pack_bf16(st[kvf][qf][2], st[kvf][qf][3]);
      }
      rs += __shfl_xor(rs, 16);
      rs += __shfl_xor(rs, 32);
      l_[qf] += rs;
    }

    // O^T += V^T P : A = Vt rows (d), k = kv (granularity 4 -> 16x16x16)
#pragma unroll
    for (int kvc = 0; kvc < 4; ++kvc) {
#pragma unroll
      for (int df = 0; df < 4; ++df) {
        int r = df * 16 + lg;
        int byte_ = r * 128 + ((kvc * 32 + lh * 8) ^ ((r & 7) << 4));
        s16x4 vf = *(const s16x4*)(Vl[cur] + byte_);
#pragma unroll
        for (int qf = 0; qf < 2; ++qf) {
          union { unsigned u[2]; s16x4 v; } pb;
          pb.u[0] = pw[kvc][qf][0];
          pb.u[1] = pw[kvc][qf][1];
          o_[df][qf] = __builtin_amdgcn_mfma_f32_16x16x16bf16_1k(vf, pb.v, o_[df][qf], 0, 0, 0);
        }
      }
    }
    // explicit drain of outstanding global_load_lds before the barrier (paranoia; free)
    asm volatile("s_waitcnt vmcnt(0)" ::: "memory");
    __syncthreads();
  }

  // normalize + store: O^T frag -> Ob[q][h*64+d]; i-dim is consecutive d -> 8B stores
#pragma unroll
  for (int qf = 0; qf < 2; ++qf) {
    float inv = 1.f / l_[qf];
    size_t qrow = (size_t)(qrow0 + qf * 16 + lg) * 1024 + h * 64;
#pragma unroll
    for (int df = 0; df < 4; ++df) {
      union { unsigned u[2]; unsigned long long ull; } pk;
      pk.u[0] = pack_bf16(o_[df][qf][0] * inv, o_[df][qf][1] * inv);
      pk.u[1] = pack_bf16(o_[df][qf][2] * inv, o_[df][qf][3] * inv);
      *(unsigned long long*)(Ob + qrow + df * 16 + lh * 4) = pk.ull;
    }
  }
}

extern "C" void kernel_launch(void* const* d_in, const int* in_sizes, int n_in,
                              void* d_out, int out_size, void* d_ws, size_t ws_size,
                              hipStream_t stream) {
  const float* x     = (const float*)d_in[0];
  const float* ctx   = (const float*)d_in[1];
  const float* Wq    = (const float*)d_in[2];
  const float* Wkv   = (const float*)d_in[3];
  const float* Wproj = (const float*)d_in[4];
  const float* qg    = (const float*)d_in[5];
  const float* kg    = (const float*)d_in[6];
  float* out = (float*)d_out;

  // B=4 L=4096 Lc=1024 D=1024 CTX=1024 H=16 hd=64
  char* ws = (char*)d_ws;
  unsigned short* xb   = (unsigned short*)(ws);                        // 32MB; reused as Ob
  unsigned short* cb   = (unsigned short*)(ws + (size_t)32 * 1048576); // 8MB; reused as Vt
  unsigned short* Wqt  = (unsigned short*)(ws + (size_t)40 * 1048576); // 2MB
  unsigned short* Wkvt = (unsigned short*)(ws + (size_t)42 * 1048576); // 4MB
  unsigned short* Wpt  = (unsigned short*)(ws + (size_t)46 * 1048576); // 2MB
  unsigned short* Qb   = (unsigned short*)(ws + (size_t)48 * 1048576); // 32MB
  unsigned short* KVb  = (unsigned short*)(ws + (size_t)80 * 1048576); // 16MB
  unsigned short* Vt   = cb;  // cb is dead after the KV GEMM
  unsigned short* Ob   = xb;  // xb is dead after the Q GEMM

  conv_bf16_kernel<<<16384, 256, 0, stream>>>(x, xb, 4194304);
  conv_bf16_kernel<<<4096, 256, 0, stream>>>(ctx, cb, 1048576);
  tconv_kernel<<<dim3(32, 32), dim3(32, 8), 0, stream>>>(Wq, Wqt, 1024, 1024);
  tconv_kernel<<<dim3(64, 32), dim3(32, 8), 0, stream>>>(Wkv, Wkvt, 1024, 2048);
  tconv_kernel<<<dim3(32, 32), dim3(32, 8), 0, stream>>>(Wproj, Wpt, 1024, 1024);

  gemm_kernel<1, 0><<<dim3(8, 128), 256, 0, stream>>>(xb, Wqt, Qb, 16384, 1024, 1024, qg);
  gemm_kernel<2, 0><<<dim3(16, 32), 256, 0, stream>>>(cb, Wkvt, KVb, 4096, 2048, 1024, kg);
  vtrans_kernel<<<dim3(16, 16, 4), 256, 0, stream>>>(KVb, Vt);
  flash_kernel<<<2048, 256, 0, stream>>>(Qb, KVb, Vt, Ob);
  gemm_kernel<0, 1><<<dim3(8, 128), 256, 0, stream>>>(Ob, Wpt, out, 16384, 1024, 1024, nullptr);
}

// Round 5
// 322.757 us; speedup vs baseline: 1.6468x; 1.1081x over previous
//
#include <hip/hip_runtime.h>

typedef __bf16 bf16x8 __attribute__((ext_vector_type(8)));
typedef __bf16 bf16x4 __attribute__((ext_vector_type(4)));
typedef float f32x4 __attribute__((ext_vector_type(4)));
typedef short s16x4 __attribute__((ext_vector_type(4)));

__device__ __forceinline__ void gl_lds16(const void* g, void* l) {
  __builtin_amdgcn_global_load_lds(
      (const __attribute__((address_space(1))) unsigned int*)g,
      (__attribute__((address_space(3))) unsigned int*)l, 16, 0, 0);
}

// ---------------- f32 -> bf16 convert (vectorized, native casts) ----------------
__global__ __launch_bounds__(256) void conv_bf16_kernel(
    const float* __restrict__ in, __bf16* __restrict__ out, int n4) {
  int i = blockIdx.x * 256 + threadIdx.x;
  if (i < n4) {
    float4 v = ((const float4*)in)[i];
    bf16x4 o;
    o[0] = (__bf16)v.x; o[1] = (__bf16)v.y; o[2] = (__bf16)v.z; o[3] = (__bf16)v.w;
    *(bf16x4*)(out + (size_t)i * 4) = o;
  }
}

// ---------------- f32 [R][C] -> bf16 transposed [C][R] ----------------
__global__ __launch_bounds__(256) void tconv_kernel(
    const float* __restrict__ W, __bf16* __restrict__ Wt, int R, int C) {
  __shared__ float t[32][33];
  int c0 = blockIdx.x * 32, r0 = blockIdx.y * 32;
  int tx = threadIdx.x, ty = threadIdx.y;
#pragma unroll
  for (int i = 0; i < 4; ++i)
    t[ty + i * 8][tx] = W[(size_t)(r0 + ty + i * 8) * C + c0 + tx];
  __syncthreads();
#pragma unroll
  for (int i = 0; i < 4; ++i)
    Wt[(size_t)(c0 + ty + i * 8) * R + r0 + tx] = (__bf16)t[tx][ty + i * 8];
}

// ---------------- V transpose + kv-permute: KVb[b,kv,1024+h*64+d] -> Vt[b,h,d,kvp] ----
// Within each 32-kv group, kv j stored at newpos(j) = ((j&15)>>2)*8 + (j>>4)*4 + (j&3),
// so one b128 LDS read (16B) yields the s16x4 A-fragments for kvc=2p AND kvc=2p+1.
__global__ __launch_bounds__(256) void vtrans_kernel(
    const __bf16* __restrict__ KVb, __bf16* __restrict__ Vt) {
  const int kt = blockIdx.x, h = blockIdx.y, b = blockIdx.z;
  const int tid = threadIdx.x;
#pragma unroll
  for (int it = 0; it < 2; ++it) {
    int d = (tid >> 3) + it * 32;
    int kv0 = (tid & 7) * 8;            // 8-aligned within 64
    __bf16 tmp[8];
#pragma unroll
    for (int j = 0; j < 8; ++j)
      tmp[j] = KVb[(size_t)(b * 1024 + kt * 64 + kv0 + j) * 2048 + 1024 + h * 64 + d];
    int g = kv0 & 31;
    int base = (kv0 & ~31);
    int p0 = ((g & 15) >> 2) * 8 + (g >> 4) * 4;
    int g4 = g + 4;
    int p1 = ((g4 & 15) >> 2) * 8 + (g4 >> 4) * 4;
    __bf16* dst = Vt + ((size_t)((b * 16 + h) * 64) + d) * 1024 + kt * 64 + base;
    *(bf16x4*)(dst + p0) = *(bf16x4*)(tmp);
    *(bf16x4*)(dst + p1) = *(bf16x4*)(tmp + 4);
  }
}

// ---------------- bf16 GEMM (2-phase dbuf): C[M,N] = A[M,K] * Bt[N,K]^T ----------------
template <int NORM, int OUTF32>
__global__ __launch_bounds__(256) void gemm_kernel(
    const __bf16* __restrict__ A, const __bf16* __restrict__ Bt,
    void* __restrict__ Cout, int M, int N, int K, const float* __restrict__ gamma) {
  __shared__ alignas(16) __bf16 Alds[2][128 * 32];
  __shared__ alignas(16) __bf16 Blds[2][128 * 32];
  const int tid = threadIdx.x;
  const int w = tid >> 6, l = tid & 63;
  const int lg = l & 15, lh = l >> 4;
  const int wr = w >> 1, wc = w & 1;
  const int brow = blockIdx.y * 128, bcol = blockIdx.x * 128;

  const f32x4 zero = {0.f, 0.f, 0.f, 0.f};
  f32x4 acc[4][4];
#pragma unroll
  for (int m = 0; m < 4; ++m)
#pragma unroll
    for (int n = 0; n < 4; ++n) acc[m][n] = zero;

  auto STAGE = [&](int buf, int k0) {
#pragma unroll
    for (int j = 0; j < 2; ++j) {
      int c = j * 256 + w * 64 + l;
      gl_lds16(A + (size_t)(brow + (c >> 2)) * K + k0 + (c & 3) * 8,
               (char*)Alds[buf] + (j * 256 + w * 64) * 16);
      gl_lds16(Bt + (size_t)(bcol + (c >> 2)) * K + k0 + (c & 3) * 8,
               (char*)Blds[buf] + (j * 256 + w * 64) * 16);
    }
  };

  STAGE(0, 0);
  __syncthreads();
  for (int k0 = 0; k0 < K; k0 += 32) {
    int cur = (k0 >> 5) & 1;
    if (k0 + 32 < K) STAGE(cur ^ 1, k0 + 32);
    bf16x8 af[4], bfr[4];
#pragma unroll
    for (int m = 0; m < 4; ++m)
      af[m] = *(const bf16x8*)(Alds[cur] + (wr * 64 + m * 16 + lg) * 32 + lh * 8);
#pragma unroll
    for (int n = 0; n < 4; ++n)
      bfr[n] = *(const bf16x8*)(Blds[cur] + (wc * 64 + n * 16 + lg) * 32 + lh * 8);
#pragma unroll
    for (int m = 0; m < 4; ++m)
#pragma unroll
      for (int n = 0; n < 4; ++n)
        acc[m][n] = __builtin_amdgcn_mfma_f32_16x16x32_bf16(af[m], bfr[n], acc[m][n], 0, 0, 0);
    __syncthreads();
  }

  if (NORM == 1 || (NORM == 2 && (bcol + wc * 64) < 1024)) {
    float gm[4];
#pragma unroll
    for (int n = 0; n < 4; ++n) gm[n] = gamma[n * 16 + lg];
#pragma unroll
    for (int m = 0; m < 4; ++m) {
#pragma unroll
      for (int i = 0; i < 4; ++i) {
        float ss = 0.f;
#pragma unroll
        for (int n = 0; n < 4; ++n) ss += acc[m][n][i] * acc[m][n][i];
        ss += __shfl_xor(ss, 1);
        ss += __shfl_xor(ss, 2);
        ss += __shfl_xor(ss, 4);
        ss += __shfl_xor(ss, 8);
        float inv = rsqrtf(ss * (1.0f / 64.0f) + 1e-6f);
#pragma unroll
        for (int n = 0; n < 4; ++n) acc[m][n][i] *= inv * gm[n];
      }
    }
  }

#pragma unroll
  for (int m = 0; m < 4; ++m)
#pragma unroll
    for (int n = 0; n < 4; ++n)
#pragma unroll
      for (int i = 0; i < 4; ++i) {
        size_t idx = (size_t)(brow + wr * 64 + m * 16 + lh * 4 + i) * N +
                     bcol + wc * 64 + n * 16 + lg;
        if (OUTF32) ((float*)Cout)[idx] = acc[m][n][i];
        else ((__bf16*)Cout)[idx] = (__bf16)acc[m][n][i];
      }
}

// ---------------- flash attention v5: swapped QK^T, in-reg P, native casts, raw exp2 ----
__global__ __launch_bounds__(256) void flash_kernel(
    const __bf16* __restrict__ Qb, const __bf16* __restrict__ KVb,
    const __bf16* __restrict__ Vt, __bf16* __restrict__ Ob) {
  // XCD-aware bijective swizzle: 2048 blocks, 8 XCDs, 256 per XCD.
  const int orig = blockIdx.x;
  const int wgid = (orig & 7) * 256 + (orig >> 3);
  const int qt = wgid & 31, h = (wgid >> 5) & 15, b = wgid >> 9;
  const int tid = threadIdx.x;
  const int w = tid >> 6, l = tid & 63, lg = l & 15, lh = l >> 4;
  __shared__ alignas(16) char Kl[2][8192];   // [kv 64][d 64] bf16, XOR-swizzled
  __shared__ alignas(16) char Vl[2][8192];   // [d 64][kvp 64] bf16, XOR-swizzled

  const int qrow0 = b * 4096 + qt * 128 + w * 32;
  bf16x8 qfr[2][2];
#pragma unroll
  for (int mff = 0; mff < 2; ++mff)
#pragma unroll
    for (int dc = 0; dc < 2; ++dc)
      qfr[mff][dc] = *(const bf16x8*)(Qb + (size_t)(qrow0 + mff * 16 + lg) * 1024 +
                                      h * 64 + dc * 32 + lh * 8);

  const char* Kg = (const char*)KVb + (size_t)b * 1024 * 4096 + h * 128;  // row stride 4096B
  const char* Vg = (const char*)Vt + (size_t)(b * 16 + h) * 64 * 2048;    // row stride 2048B

  auto STAGE = [&](int buf, int kt) {
#pragma unroll
    for (int c = 0; c < 2; ++c) {
      int o = (c * 256 + tid) * 16;                // per-lane LDS byte offset in tile
      int op = o ^ (((o >> 7) & 7) << 4);          // pre-swizzled source offset
      int row = op >> 7, cb = op & 127;
      gl_lds16(Kg + (size_t)(kt * 64 + row) * 4096 + cb, Kl[buf] + (c * 256 + w * 64) * 16);
      gl_lds16(Vg + (size_t)row * 2048 + kt * 128 + cb, Vl[buf] + (c * 256 + w * 64) * 16);
    }
  };

  const f32x4 zero = {0.f, 0.f, 0.f, 0.f};
  f32x4 o_[4][2];   // [df][qf] : O^T frag, row d = df*16+lh*4+i, col q = qf*16+lg
  float m_[2], l_[2];
#pragma unroll
  for (int df = 0; df < 4; ++df)
#pragma unroll
    for (int qf = 0; qf < 2; ++qf) o_[df][qf] = zero;
  m_[0] = m_[1] = -1e30f;
  l_[0] = l_[1] = 0.f;

  const float C = 0.18033688f;   // log2(e)/sqrt(64)

  STAGE(0, 0);
  __syncthreads();
  for (int kt = 0; kt < 16; ++kt) {
    const int cur = kt & 1;
    if (kt < 15) STAGE(cur ^ 1, kt + 1);

    // S^T[kv][q] : A = K rows (kv), B = Q cols (q)
    f32x4 st[4][2];
#pragma unroll
    for (int kvf = 0; kvf < 4; ++kvf)
#pragma unroll
      for (int mff = 0; mff < 2; ++mff) st[kvf][mff] = zero;
#pragma unroll
    for (int dc = 0; dc < 2; ++dc)
#pragma unroll
      for (int kvf = 0; kvf < 4; ++kvf) {
        int r = kvf * 16 + lg;
        int byte_ = (r * 128 + dc * 64 + lh * 16) ^ ((r & 7) << 4);
        bf16x8 kf = *(const bf16x8*)(Kl[cur] + byte_);
#pragma unroll
        for (int mff = 0; mff < 2; ++mff)
          st[kvf][mff] = __builtin_amdgcn_mfma_f32_16x16x32_bf16(kf, qfr[mff][dc], st[kvf][mff], 0, 0, 0);
      }

    // row-max per q (lane-local 16, then xor16/32 across lh groups)
    float pmax[2];
#pragma unroll
    for (int qf = 0; qf < 2; ++qf) {
      float t = st[0][qf][0];
#pragma unroll
      for (int kvf = 0; kvf < 4; ++kvf)
#pragma unroll
        for (int i = 0; i < 4; ++i) t = fmaxf(t, st[kvf][qf][i]);
      t = fmaxf(t, __shfl_xor(t, 16));
      t = fmaxf(t, __shfl_xor(t, 32));
      pmax[qf] = t;
    }

    // online-softmax rescale every tile
#pragma unroll
    for (int qf = 0; qf < 2; ++qf) {
      float nm = fmaxf(m_[qf], pmax[qf]);
      float r = __builtin_amdgcn_exp2f((m_[qf] - nm) * C);
      m_[qf] = nm;
      l_[qf] *= r;
#pragma unroll
      for (int df = 0; df < 4; ++df)
#pragma unroll
        for (int i = 0; i < 4; ++i) o_[df][qf][i] *= r;
    }

    // P = exp2((s-m)*C), row-sum, native-cast pack to bf16 B-fragments
    bf16x4 pb[4][2];
#pragma unroll
    for (int qf = 0; qf < 2; ++qf) {
      float rs = 0.f;
      float mc = -m_[qf] * C;
#pragma unroll
      for (int kvf = 0; kvf < 4; ++kvf) {
#pragma unroll
        for (int i = 0; i < 4; ++i) {
          float p = __builtin_amdgcn_exp2f(fmaf(st[kvf][qf][i], C, mc));
          pb[kvf][qf][i] = (__bf16)p;
          rs += p;
        }
      }
      rs += __shfl_xor(rs, 16);
      rs += __shfl_xor(rs, 32);
      l_[qf] += rs;
    }

    // O^T += V^T P : one b128 V read yields fragments for kvc=2p and 2p+1
#pragma unroll
    for (int p = 0; p < 2; ++p) {
#pragma unroll
      for (int df = 0; df < 4; ++df) {
        int r = df * 16 + lg;
        int byte_ = r * 128 + ((p * 64 + lh * 16) ^ ((r & 7) << 4));
        union { bf16x8 v8; s16x4 h[2]; } u;
        u.v8 = *(const bf16x8*)(Vl[cur] + byte_);
#pragma unroll
        for (int qf = 0; qf < 2; ++qf) {
          union { bf16x4 b; s16x4 s; } plo, phi;
          plo.b = pb[2 * p][qf];
          phi.b = pb[2 * p + 1][qf];
          o_[df][qf] = __builtin_amdgcn_mfma_f32_16x16x16bf16_1k(u.h[0], plo.s, o_[df][qf], 0, 0, 0);
          o_[df][qf] = __builtin_amdgcn_mfma_f32_16x16x16bf16_1k(u.h[1], phi.s, o_[df][qf], 0, 0, 0);
        }
      }
    }
    // explicit drain of outstanding global_load_lds before the barrier (kept from v4)
    asm volatile("s_waitcnt vmcnt(0)" ::: "memory");
    __syncthreads();
  }

  // normalize + store: O^T frag -> Ob[q][h*64+d]; i-dim is consecutive d -> 8B stores
#pragma unroll
  for (int qf = 0; qf < 2; ++qf) {
    float inv = 1.f / l_[qf];
    size_t qrow = (size_t)(qrow0 + qf * 16 + lg) * 1024 + h * 64;
#pragma unroll
    for (int df = 0; df < 4; ++df) {
      bf16x4 ov;
#pragma unroll
      for (int i = 0; i < 4; ++i) ov[i] = (__bf16)(o_[df][qf][i] * inv);
      *(bf16x4*)(Ob + qrow + df * 16 + lh * 4) = ov;
    }
  }
}

extern "C" void kernel_launch(void* const* d_in, const int* in_sizes, int n_in,
                              void* d_out, int out_size, void* d_ws, size_t ws_size,
                              hipStream_t stream) {
  const float* x     = (const float*)d_in[0];
  const float* ctx   = (const float*)d_in[1];
  const float* Wq    = (const float*)d_in[2];
  const float* Wkv   = (const float*)d_in[3];
  const float* Wproj = (const float*)d_in[4];
  const float* qg    = (const float*)d_in[5];
  const float* kg    = (const float*)d_in[6];
  float* out = (float*)d_out;

  // B=4 L=4096 Lc=1024 D=1024 CTX=1024 H=16 hd=64
  char* ws = (char*)d_ws;
  __bf16* xb   = (__bf16*)(ws);                        // 32MB; reused as Ob
  __bf16* cb   = (__bf16*)(ws + (size_t)32 * 1048576); // 8MB; reused as Vt
  __bf16* Wqt  = (__bf16*)(ws + (size_t)40 * 1048576); // 2MB
  __bf16* Wkvt = (__bf16*)(ws + (size_t)42 * 1048576); // 4MB
  __bf16* Wpt  = (__bf16*)(ws + (size_t)46 * 1048576); // 2MB
  __bf16* Qb   = (__bf16*)(ws + (size_t)48 * 1048576); // 32MB
  __bf16* KVb  = (__bf16*)(ws + (size_t)80 * 1048576); // 16MB
  __bf16* Vt   = cb;  // cb is dead after the KV GEMM
  __bf16* Ob   = xb;  // xb is dead after the Q GEMM

  conv_bf16_kernel<<<16384, 256, 0, stream>>>(x, xb, 4194304);
  conv_bf16_kernel<<<4096, 256, 0, stream>>>(ctx, cb, 1048576);
  tconv_kernel<<<dim3(32, 32), dim3(32, 8), 0, stream>>>(Wq, Wqt, 1024, 1024);
  tconv_kernel<<<dim3(64, 32), dim3(32, 8), 0, stream>>>(Wkv, Wkvt, 1024, 2048);
  tconv_kernel<<<dim3(32, 32), dim3(32, 8), 0, stream>>>(Wproj, Wpt, 1024, 1024);

  gemm_kernel<1, 0><<<dim3(8, 128), 256, 0, stream>>>(xb, Wqt, Qb, 16384, 1024, 1024, qg);
  gemm_kernel<2, 0><<<dim3(16, 32), 256, 0, stream>>>(cb, Wkvt, KVb, 4096, 2048, 1024, kg);
  vtrans_kernel<<<dim3(16, 16, 4), 256, 0, stream>>>(KVb, Vt);
  flash_kernel<<<2048, 256, 0, stream>>>(Qb, KVb, Vt, Ob);
  gemm_kernel<0, 1><<<dim3(8, 128), 256, 0, stream>>>(Ob, Wpt, out, 16384, 1024, 1024, nullptr);
}

// Round 6
// 316.579 us; speedup vs baseline: 1.6790x; 1.0195x over previous
//
#include <hip/hip_runtime.h>

typedef __bf16 bf16x8 __attribute__((ext_vector_type(8)));
typedef __bf16 bf16x4 __attribute__((ext_vector_type(4)));
typedef float f32x4 __attribute__((ext_vector_type(4)));
typedef short s16x4 __attribute__((ext_vector_type(4)));

__device__ __forceinline__ void gl_lds16(const void* g, void* l) {
  __builtin_amdgcn_global_load_lds(
      (const __attribute__((address_space(1))) unsigned int*)g,
      (__attribute__((address_space(3))) unsigned int*)l, 16, 0, 0);
}

// ---------------- f32 -> bf16 convert (vectorized, native casts) ----------------
__global__ __launch_bounds__(256) void conv_bf16_kernel(
    const float* __restrict__ in, __bf16* __restrict__ out, int n4) {
  int i = blockIdx.x * 256 + threadIdx.x;
  if (i < n4) {
    float4 v = ((const float4*)in)[i];
    bf16x4 o;
    o[0] = (__bf16)v.x; o[1] = (__bf16)v.y; o[2] = (__bf16)v.z; o[3] = (__bf16)v.w;
    *(bf16x4*)(out + (size_t)i * 4) = o;
  }
}

// ---------------- f32 [R][C] -> bf16 transposed [C][R] ----------------
__global__ __launch_bounds__(256) void tconv_kernel(
    const float* __restrict__ W, __bf16* __restrict__ Wt, int R, int C) {
  __shared__ float t[32][33];
  int c0 = blockIdx.x * 32, r0 = blockIdx.y * 32;
  int tx = threadIdx.x, ty = threadIdx.y;
#pragma unroll
  for (int i = 0; i < 4; ++i)
    t[ty + i * 8][tx] = W[(size_t)(r0 + ty + i * 8) * C + c0 + tx];
  __syncthreads();
#pragma unroll
  for (int i = 0; i < 4; ++i)
    Wt[(size_t)(c0 + ty + i * 8) * R + r0 + tx] = (__bf16)t[tx][ty + i * 8];
}

// ---------------- bf16 GEMM (2-phase dbuf): C[M,N] = A[M,K] * Bt[N,K]^T ----------------
// NORM==1: per-64-col RMSNorm (q), plain write to Cout [M,N] bf16
// NORM==2: KV mode. cols<1024: RMSNorm + write K to Cout as [M,1024] bf16 (compact).
//          cols>=1024: write V transposed+kv-permuted to Cout2 = Vt[b,h,d,kvp].
// NORM==0: plain; OUTF32 selects f32 output.
template <int NORM, int OUTF32>
__global__ __launch_bounds__(256) void gemm_kernel(
    const __bf16* __restrict__ A, const __bf16* __restrict__ Bt,
    void* __restrict__ Cout, void* __restrict__ Cout2,
    int M, int N, int K, const float* __restrict__ gamma) {
  __shared__ alignas(16) __bf16 Alds[2][128 * 32];
  __shared__ alignas(16) __bf16 Blds[2][128 * 32];
  const int tid = threadIdx.x;
  const int w = tid >> 6, l = tid & 63;
  const int lg = l & 15, lh = l >> 4;
  const int wr = w >> 1, wc = w & 1;
  const int brow = blockIdx.y * 128, bcol = blockIdx.x * 128;

  const f32x4 zero = {0.f, 0.f, 0.f, 0.f};
  f32x4 acc[4][4];
#pragma unroll
  for (int m = 0; m < 4; ++m)
#pragma unroll
    for (int n = 0; n < 4; ++n) acc[m][n] = zero;

  auto STAGE = [&](int buf, int k0) {
#pragma unroll
    for (int j = 0; j < 2; ++j) {
      int c = j * 256 + w * 64 + l;
      gl_lds16(A + (size_t)(brow + (c >> 2)) * K + k0 + (c & 3) * 8,
               (char*)Alds[buf] + (j * 256 + w * 64) * 16);
      gl_lds16(Bt + (size_t)(bcol + (c >> 2)) * K + k0 + (c & 3) * 8,
               (char*)Blds[buf] + (j * 256 + w * 64) * 16);
    }
  };

  STAGE(0, 0);
  __syncthreads();
  for (int k0 = 0; k0 < K; k0 += 32) {
    int cur = (k0 >> 5) & 1;
    if (k0 + 32 < K) STAGE(cur ^ 1, k0 + 32);
    bf16x8 af[4], bfr[4];
#pragma unroll
    for (int m = 0; m < 4; ++m)
      af[m] = *(const bf16x8*)(Alds[cur] + (wr * 64 + m * 16 + lg) * 32 + lh * 8);
#pragma unroll
    for (int n = 0; n < 4; ++n)
      bfr[n] = *(const bf16x8*)(Blds[cur] + (wc * 64 + n * 16 + lg) * 32 + lh * 8);
#pragma unroll
    for (int m = 0; m < 4; ++m)
#pragma unroll
      for (int n = 0; n < 4; ++n)
        acc[m][n] = __builtin_amdgcn_mfma_f32_16x16x32_bf16(af[m], bfr[n], acc[m][n], 0, 0, 0);
    __syncthreads();
  }

  const int col64 = bcol + wc * 64;
  if (NORM == 1 || (NORM == 2 && col64 < 1024)) {
    float gm[4];
#pragma unroll
    for (int n = 0; n < 4; ++n) gm[n] = gamma[n * 16 + lg];
#pragma unroll
    for (int m = 0; m < 4; ++m) {
#pragma unroll
      for (int i = 0; i < 4; ++i) {
        float ss = 0.f;
#pragma unroll
        for (int n = 0; n < 4; ++n) ss += acc[m][n][i] * acc[m][n][i];
        ss += __shfl_xor(ss, 1);
        ss += __shfl_xor(ss, 2);
        ss += __shfl_xor(ss, 4);
        ss += __shfl_xor(ss, 8);
        float inv = rsqrtf(ss * (1.0f / 64.0f) + 1e-6f);
#pragma unroll
        for (int n = 0; n < 4; ++n) acc[m][n][i] *= inv * gm[n];
      }
    }
  }

  if (NORM == 2) {
    if (col64 < 1024) {
      // K half -> compact Kb [M,1024]
#pragma unroll
      for (int m = 0; m < 4; ++m)
#pragma unroll
        for (int n = 0; n < 4; ++n)
#pragma unroll
          for (int i = 0; i < 4; ++i) {
            size_t idx = (size_t)(brow + wr * 64 + m * 16 + lh * 4 + i) * 1024 +
                         col64 + n * 16 + lg;
            ((__bf16*)Cout)[idx] = (__bf16)acc[m][n][i];
          }
    } else {
      // V half -> Vt[b,h,d,kvp]: i-dim = 4 consecutive kv = contiguous after permute
#pragma unroll
      for (int m = 0; m < 4; ++m) {
        int row = brow + wr * 64 + m * 16 + lh * 4;   // global ctx row = b*1024 + kv
        int bb = row >> 10, kv0 = row & 1023;
        int g = kv0 & 31;
        int pos = (kv0 & ~31) + ((g & 15) >> 2) * 8 + (g >> 4) * 4;
#pragma unroll
        for (int n = 0; n < 4; ++n) {
          int col = col64 + n * 16 + lg - 1024;       // = h*64 + d
          bf16x4 v;
#pragma unroll
          for (int i = 0; i < 4; ++i) v[i] = (__bf16)acc[m][n][i];
          *(bf16x4*)((__bf16*)Cout2 + ((size_t)(bb * 1024 + col)) * 1024 + pos) = v;
        }
      }
    }
    return;
  }

#pragma unroll
  for (int m = 0; m < 4; ++m)
#pragma unroll
    for (int n = 0; n < 4; ++n)
#pragma unroll
      for (int i = 0; i < 4; ++i) {
        size_t idx = (size_t)(brow + wr * 64 + m * 16 + lh * 4 + i) * N +
                     bcol + wc * 64 + n * 16 + lg;
        if (OUTF32) ((float*)Cout)[idx] = acc[m][n][i];
        else ((__bf16*)Cout)[idx] = (__bf16)acc[m][n][i];
      }
}

// ---------------- flash attention v6: 8 waves/block, defer-max, deferred l-reduce ----
__global__ __launch_bounds__(512) void flash_kernel(
    const __bf16* __restrict__ Qb, const __bf16* __restrict__ Kb,
    const __bf16* __restrict__ Vt, __bf16* __restrict__ Ob) {
  // XCD-aware bijective swizzle: 1024 blocks, 8 XCDs, 128 per XCD.
  const int orig = blockIdx.x;
  const int wgid = (orig & 7) * 128 + (orig >> 3);
  const int qt = wgid & 15, h = (wgid >> 4) & 15, b = wgid >> 8;
  const int tid = threadIdx.x;
  const int w = tid >> 6, l = tid & 63, lg = l & 15, lh = l >> 4;
  __shared__ alignas(16) char Kl[2][8192];   // [kv 64][d 64] bf16, XOR-swizzled
  __shared__ alignas(16) char Vl[2][8192];   // [d 64][kvp 64] bf16, XOR-swizzled

  const int qrow0 = b * 4096 + qt * 256 + w * 32;
  bf16x8 qfr[2][2];
#pragma unroll
  for (int mff = 0; mff < 2; ++mff)
#pragma unroll
    for (int dc = 0; dc < 2; ++dc)
      qfr[mff][dc] = *(const bf16x8*)(Qb + (size_t)(qrow0 + mff * 16 + lg) * 1024 +
                                      h * 64 + dc * 32 + lh * 8);

  const char* Kg = (const char*)Kb + (size_t)b * 2097152 + h * 128;  // row stride 2048B
  const char* Vg = (const char*)Vt + (size_t)(b * 16 + h) * 64 * 2048;

  // per-thread (512 thr): 1 K-load + 1 V-load per tile; linear LDS dest, pre-swizzled src
  const int o16 = tid * 16;
  const int op = o16 ^ (((o16 >> 7) & 7) << 4);
  const int srow = op >> 7, scb = op & 127;

  auto STAGE = [&](int buf, int kt) {
    gl_lds16(Kg + (size_t)(kt * 64 + srow) * 2048 + scb, Kl[buf] + w * 1024);
    gl_lds16(Vg + (size_t)srow * 2048 + kt * 128 + scb, Vl[buf] + w * 1024);
  };

  const f32x4 zero = {0.f, 0.f, 0.f, 0.f};
  f32x4 o_[4][2];   // [df][qf] : O^T frag, row d = df*16+lh*4+i, col q = qf*16+lg
  float m_[2], lp_[2];
#pragma unroll
  for (int df = 0; df < 4; ++df)
#pragma unroll
    for (int qf = 0; qf < 2; ++qf) o_[df][qf] = zero;
  m_[0] = m_[1] = -1e30f;
  lp_[0] = lp_[1] = 0.f;

  const float C = 0.18033688f;   // log2(e)/sqrt(64)
  const float DT = 44.361f;      // 8/C -> P bounded by 2^8

  STAGE(0, 0);
  __syncthreads();
  for (int kt = 0; kt < 16; ++kt) {
    const int cur = kt & 1;
    if (kt < 15) STAGE(cur ^ 1, kt + 1);

    // S^T[kv][q] : A = K rows (kv), B = Q cols (q)
    f32x4 st[4][2];
#pragma unroll
    for (int kvf = 0; kvf < 4; ++kvf)
#pragma unroll
      for (int mff = 0; mff < 2; ++mff) st[kvf][mff] = zero;
#pragma unroll
    for (int dc = 0; dc < 2; ++dc)
#pragma unroll
      for (int kvf = 0; kvf < 4; ++kvf) {
        int r = kvf * 16 + lg;
        int byte_ = (r * 128 + dc * 64 + lh * 16) ^ ((r & 7) << 4);
        bf16x8 kf = *(const bf16x8*)(Kl[cur] + byte_);
#pragma unroll
        for (int mff = 0; mff < 2; ++mff)
          st[kvf][mff] = __builtin_amdgcn_mfma_f32_16x16x32_bf16(kf, qfr[mff][dc], st[kvf][mff], 0, 0, 0);
      }

    // row-max per q: pairwise tree over kvf, then horizontal, then xor16/32
    float pmax[2];
#pragma unroll
    for (int qf = 0; qf < 2; ++qf) {
      float ma[4];
#pragma unroll
      for (int i = 0; i < 4; ++i)
        ma[i] = fmaxf(fmaxf(st[0][qf][i], st[1][qf][i]),
                      fmaxf(st[2][qf][i], st[3][qf][i]));
      float t = fmaxf(fmaxf(ma[0], ma[1]), fmaxf(ma[2], ma[3]));
      t = fmaxf(t, __shfl_xor(t, 16));
      t = fmaxf(t, __shfl_xor(t, 32));
      pmax[qf] = t;
    }

    // defer-max: rescale only when a row grew past threshold (wave-uniform branch)
    int need = (pmax[0] - m_[0] > DT) || (pmax[1] - m_[1] > DT);
    if (__any(need)) {
#pragma unroll
      for (int qf = 0; qf < 2; ++qf) {
        float nm = fmaxf(m_[qf], pmax[qf]);
        float r = __builtin_amdgcn_exp2f((m_[qf] - nm) * C);
        m_[qf] = nm;
        lp_[qf] *= r;
#pragma unroll
        for (int df = 0; df < 4; ++df)
#pragma unroll
          for (int i = 0; i < 4; ++i) o_[df][qf][i] *= r;
      }
    }

    // P = exp2((s-m)*C), per-lane partial row-sum, native-cast pack to bf16
    bf16x4 pb[4][2];
#pragma unroll
    for (int qf = 0; qf < 2; ++qf) {
      float rs = 0.f;
      float mc = -m_[qf] * C;
#pragma unroll
      for (int kvf = 0; kvf < 4; ++kvf) {
#pragma unroll
        for (int i = 0; i < 4; ++i) {
          float p = __builtin_amdgcn_exp2f(fmaf(st[kvf][qf][i], C, mc));
          pb[kvf][qf][i] = (__bf16)p;
          rs += p;
        }
      }
      lp_[qf] += rs;   // cross-lane reduce deferred to epilogue
    }

    // O^T += V^T P : one b128 V read yields fragments for kvc=2p and 2p+1
#pragma unroll
    for (int p = 0; p < 2; ++p) {
#pragma unroll
      for (int df = 0; df < 4; ++df) {
        int r = df * 16 + lg;
        int byte_ = r * 128 + ((p * 64 + lh * 16) ^ ((r & 7) << 4));
        union { bf16x8 v8; s16x4 hh[2]; } u;
        u.v8 = *(const bf16x8*)(Vl[cur] + byte_);
#pragma unroll
        for (int qf = 0; qf < 2; ++qf) {
          union { bf16x4 bv; s16x4 sv; } plo, phi;
          plo.bv = pb[2 * p][qf];
          phi.bv = pb[2 * p + 1][qf];
          o_[df][qf] = __builtin_amdgcn_mfma_f32_16x16x16bf16_1k(u.hh[0], plo.sv, o_[df][qf], 0, 0, 0);
          o_[df][qf] = __builtin_amdgcn_mfma_f32_16x16x16bf16_1k(u.hh[1], phi.sv, o_[df][qf], 0, 0, 0);
        }
      }
    }
    // explicit drain of outstanding global_load_lds before the barrier
    asm volatile("s_waitcnt vmcnt(0)" ::: "memory");
    __syncthreads();
  }

  // final l reduce + normalize + store (i-dim = consecutive d -> 8B stores)
#pragma unroll
  for (int qf = 0; qf < 2; ++qf) {
    float ls = lp_[qf];
    ls += __shfl_xor(ls, 16);
    ls += __shfl_xor(ls, 32);
    float inv = 1.f / ls;
    size_t qrow = (size_t)(qrow0 + qf * 16 + lg) * 1024 + h * 64;
#pragma unroll
    for (int df = 0; df < 4; ++df) {
      bf16x4 ov;
#pragma unroll
      for (int i = 0; i < 4; ++i) ov[i] = (__bf16)(o_[df][qf][i] * inv);
      *(bf16x4*)(Ob + qrow + df * 16 + lh * 4) = ov;
    }
  }
}

extern "C" void kernel_launch(void* const* d_in, const int* in_sizes, int n_in,
                              void* d_out, int out_size, void* d_ws, size_t ws_size,
                              hipStream_t stream) {
  const float* x     = (const float*)d_in[0];
  const float* ctx   = (const float*)d_in[1];
  const float* Wq    = (const float*)d_in[2];
  const float* Wkv   = (const float*)d_in[3];
  const float* Wproj = (const float*)d_in[4];
  const float* qg    = (const float*)d_in[5];
  const float* kg    = (const float*)d_in[6];
  float* out = (float*)d_out;

  // B=4 L=4096 Lc=1024 D=1024 CTX=1024 H=16 hd=64
  char* ws = (char*)d_ws;
  __bf16* xb   = (__bf16*)(ws);                        // 32MB; reused as Ob
  __bf16* cb   = (__bf16*)(ws + (size_t)32 * 1048576); // 8MB
  __bf16* Wqt  = (__bf16*)(ws + (size_t)40 * 1048576); // 2MB
  __bf16* Wkvt = (__bf16*)(ws + (size_t)42 * 1048576); // 4MB
  __bf16* Wpt  = (__bf16*)(ws + (size_t)46 * 1048576); // 2MB
  __bf16* Qb   = (__bf16*)(ws + (size_t)48 * 1048576); // 32MB
  __bf16* Kb   = (__bf16*)(ws + (size_t)80 * 1048576); // 8MB  [4096,1024]
  __bf16* Vt   = (__bf16*)(ws + (size_t)88 * 1048576); // 8MB  [b,h,d,kvp]
  __bf16* Ob   = xb;  // xb is dead after the Q GEMM

  conv_bf16_kernel<<<16384, 256, 0, stream>>>(x, xb, 4194304);
  conv_bf16_kernel<<<4096, 256, 0, stream>>>(ctx, cb, 1048576);
  tconv_kernel<<<dim3(32, 32), dim3(32, 8), 0, stream>>>(Wq, Wqt, 1024, 1024);
  tconv_kernel<<<dim3(64, 32), dim3(32, 8), 0, stream>>>(Wkv, Wkvt, 1024, 2048);
  tconv_kernel<<<dim3(32, 32), dim3(32, 8), 0, stream>>>(Wproj, Wpt, 1024, 1024);

  gemm_kernel<1, 0><<<dim3(8, 128), 256, 0, stream>>>(xb, Wqt, Qb, nullptr, 16384, 1024, 1024, qg);
  gemm_kernel<2, 0><<<dim3(16, 32), 256, 0, stream>>>(cb, Wkvt, Kb, Vt, 4096, 2048, 1024, kg);
  flash_kernel<<<1024, 512, 0, stream>>>(Qb, Kb, Vt, Ob);
  gemm_kernel<0, 1><<<dim3(8, 128), 256, 0, stream>>>(Ob, Wpt, out, nullptr, 16384, 1024, 1024, nullptr);
}

// Round 7
// 277.846 us; speedup vs baseline: 1.9130x; 1.1394x over previous
//
#include <hip/hip_runtime.h>

typedef __bf16 bf16x8 __attribute__((ext_vector_type(8)));
typedef __bf16 bf16x4 __attribute__((ext_vector_type(4)));
typedef float f32x4 __attribute__((ext_vector_type(4)));

__device__ __forceinline__ void gl_lds16(const void* g, void* l) {
  __builtin_amdgcn_global_load_lds(
      (const __attribute__((address_space(1))) unsigned int*)g,
      (__attribute__((address_space(3))) unsigned int*)l, 16, 0, 0);
}

// ---------------- f32 -> bf16 convert (vectorized, native casts) ----------------
__global__ __launch_bounds__(256) void conv_bf16_kernel(
    const float* __restrict__ in, __bf16* __restrict__ out, int n4) {
  int i = blockIdx.x * 256 + threadIdx.x;
  if (i < n4) {
    float4 v = ((const float4*)in)[i];
    bf16x4 o;
    o[0] = (__bf16)v.x; o[1] = (__bf16)v.y; o[2] = (__bf16)v.z; o[3] = (__bf16)v.w;
    *(bf16x4*)(out + (size_t)i * 4) = o;
  }
}

// ---------------- f32 [R][C] -> bf16 transposed [C][R] ----------------
__global__ __launch_bounds__(256) void tconv_kernel(
    const float* __restrict__ W, __bf16* __restrict__ Wt, int R, int C) {
  __shared__ float t[32][33];
  int c0 = blockIdx.x * 32, r0 = blockIdx.y * 32;
  int tx = threadIdx.x, ty = threadIdx.y;
#pragma unroll
  for (int i = 0; i < 4; ++i)
    t[ty + i * 8][tx] = W[(size_t)(r0 + ty + i * 8) * C + c0 + tx];
  __syncthreads();
#pragma unroll
  for (int i = 0; i < 4; ++i)
    Wt[(size_t)(c0 + ty + i * 8) * R + r0 + tx] = (__bf16)t[tx][ty + i * 8];
}

// ---------------- bf16 GEMM (2-phase dbuf): C[M,N] = A[M,K] * Bt[N,K]^T ----------------
// NORM==1: per-64-col RMSNorm (q), plain write to Cout [M,N] bf16
// NORM==2: KV mode. cols<1024: RMSNorm + write K to Cout as [M,1024] bf16 (compact).
//          cols>=1024: write V transposed+kv-permuted to Cout2 = Vt[b,h,d,kvp].
// NORM==0: plain; OUTF32 selects f32 output.
template <int NORM, int OUTF32>
__global__ __launch_bounds__(256) void gemm_kernel(
    const __bf16* __restrict__ A, const __bf16* __restrict__ Bt,
    void* __restrict__ Cout, void* __restrict__ Cout2,
    int M, int N, int K, const float* __restrict__ gamma) {
  __shared__ alignas(16) __bf16 Alds[2][128 * 32];
  __shared__ alignas(16) __bf16 Blds[2][128 * 32];
  const int tid = threadIdx.x;
  const int w = tid >> 6, l = tid & 63;
  const int lg = l & 15, lh = l >> 4;
  const int wr = w >> 1, wc = w & 1;
  const int brow = blockIdx.y * 128, bcol = blockIdx.x * 128;

  const f32x4 zero = {0.f, 0.f, 0.f, 0.f};
  f32x4 acc[4][4];
#pragma unroll
  for (int m = 0; m < 4; ++m)
#pragma unroll
    for (int n = 0; n < 4; ++n) acc[m][n] = zero;

  auto STAGE = [&](int buf, int k0) {
#pragma unroll
    for (int j = 0; j < 2; ++j) {
      int c = j * 256 + w * 64 + l;
      gl_lds16(A + (size_t)(brow + (c >> 2)) * K + k0 + (c & 3) * 8,
               (char*)Alds[buf] + (j * 256 + w * 64) * 16);
      gl_lds16(Bt + (size_t)(bcol + (c >> 2)) * K + k0 + (c & 3) * 8,
               (char*)Blds[buf] + (j * 256 + w * 64) * 16);
    }
  };

  STAGE(0, 0);
  __syncthreads();
  for (int k0 = 0; k0 < K; k0 += 32) {
    int cur = (k0 >> 5) & 1;
    if (k0 + 32 < K) STAGE(cur ^ 1, k0 + 32);
    bf16x8 af[4], bfr[4];
#pragma unroll
    for (int m = 0; m < 4; ++m)
      af[m] = *(const bf16x8*)(Alds[cur] + (wr * 64 + m * 16 + lg) * 32 + lh * 8);
#pragma unroll
    for (int n = 0; n < 4; ++n)
      bfr[n] = *(const bf16x8*)(Blds[cur] + (wc * 64 + n * 16 + lg) * 32 + lh * 8);
#pragma unroll
    for (int m = 0; m < 4; ++m)
#pragma unroll
      for (int n = 0; n < 4; ++n)
        acc[m][n] = __builtin_amdgcn_mfma_f32_16x16x32_bf16(af[m], bfr[n], acc[m][n], 0, 0, 0);
    __syncthreads();
  }

  const int col64 = bcol + wc * 64;
  if (NORM == 1 || (NORM == 2 && col64 < 1024)) {
    float gm[4];
#pragma unroll
    for (int n = 0; n < 4; ++n) gm[n] = gamma[n * 16 + lg];
#pragma unroll
    for (int m = 0; m < 4; ++m) {
#pragma unroll
      for (int i = 0; i < 4; ++i) {
        float ss = 0.f;
#pragma unroll
        for (int n = 0; n < 4; ++n) ss += acc[m][n][i] * acc[m][n][i];
        ss += __shfl_xor(ss, 1);
        ss += __shfl_xor(ss, 2);
        ss += __shfl_xor(ss, 4);
        ss += __shfl_xor(ss, 8);
        float inv = rsqrtf(ss * (1.0f / 64.0f) + 1e-6f);
#pragma unroll
        for (int n = 0; n < 4; ++n) acc[m][n][i] *= inv * gm[n];
      }
    }
  }

  if (NORM == 2) {
    if (col64 < 1024) {
#pragma unroll
      for (int m = 0; m < 4; ++m)
#pragma unroll
        for (int n = 0; n < 4; ++n)
#pragma unroll
          for (int i = 0; i < 4; ++i) {
            size_t idx = (size_t)(brow + wr * 64 + m * 16 + lh * 4 + i) * 1024 +
                         col64 + n * 16 + lg;
            ((__bf16*)Cout)[idx] = (__bf16)acc[m][n][i];
          }
    } else {
      // V half -> Vt[b,h,d,kvp]: i-dim = 4 consecutive kv = contiguous after permute
#pragma unroll
      for (int m = 0; m < 4; ++m) {
        int row = brow + wr * 64 + m * 16 + lh * 4;   // global ctx row = b*1024 + kv
        int bb = row >> 10, kv0 = row & 1023;
        int g = kv0 & 31;
        int pos = (kv0 & ~31) + ((g & 15) >> 2) * 8 + (g >> 4) * 4;
#pragma unroll
        for (int n = 0; n < 4; ++n) {
          int col = col64 + n * 16 + lg - 1024;       // = h*64 + d
          bf16x4 v;
#pragma unroll
          for (int i = 0; i < 4; ++i) v[i] = (__bf16)acc[m][n][i];
          *(bf16x4*)((__bf16*)Cout2 + ((size_t)(bb * 1024 + col)) * 1024 + pos) = v;
        }
      }
    }
    return;
  }

#pragma unroll
  for (int m = 0; m < 4; ++m)
#pragma unroll
    for (int n = 0; n < 4; ++n)
#pragma unroll
      for (int i = 0; i < 4; ++i) {
        size_t idx = (size_t)(brow + wr * 64 + m * 16 + lh * 4 + i) * N +
                     bcol + wc * 64 + n * 16 + lg;
        if (OUTF32) ((float*)Cout)[idx] = acc[m][n][i];
        else ((__bf16*)Cout)[idx] = (__bf16)acc[m][n][i];
      }
}

// ---------------- flash attention v7: K32 PV, hoisted LDS addrs, setprio ----------------
__global__ __launch_bounds__(512) void flash_kernel(
    const __bf16* __restrict__ Qb, const __bf16* __restrict__ Kb,
    const __bf16* __restrict__ Vt, __bf16* __restrict__ Ob) {
  // XCD-aware bijective swizzle: 1024 blocks, 8 XCDs, 128 per XCD.
  const int orig = blockIdx.x;
  const int wgid = (orig & 7) * 128 + (orig >> 3);
  const int qt = wgid & 15, h = (wgid >> 4) & 15, b = wgid >> 8;
  const int tid = threadIdx.x;
  const int w = tid >> 6, l = tid & 63, lg = l & 15, lh = l >> 4;
  // layout: K[cur] at cur*8192, V[cur] at 16384 + cur*8192
  __shared__ alignas(16) char lds[32768];

  const int qrow0 = b * 4096 + qt * 256 + w * 32;
  bf16x8 qfr[2][2];
#pragma unroll
  for (int mff = 0; mff < 2; ++mff)
#pragma unroll
    for (int dc = 0; dc < 2; ++dc)
      qfr[mff][dc] = *(const bf16x8*)(Qb + (size_t)(qrow0 + mff * 16 + lg) * 1024 +
                                      h * 64 + dc * 32 + lh * 8);

  const char* Kg = (const char*)Kb + (size_t)b * 2097152 + h * 128;  // row stride 2048B
  const char* Vg = (const char*)Vt + (size_t)(b * 16 + h) * 64 * 2048;

  // staging: per-thread 1 K-load + 1 V-load; linear LDS dest, pre-swizzled source
  const int o16 = tid * 16;
  const int op = o16 ^ (((o16 >> 7) & 7) << 4);
  const int srow = op >> 7, scb = op & 127;

  auto STAGE = [&](int buf, int kt) {
    gl_lds16(Kg + (size_t)(kt * 64 + srow) * 2048 + scb, lds + buf * 8192 + w * 1024);
    gl_lds16(Vg + (size_t)srow * 2048 + kt * 128 + scb, lds + 16384 + buf * 8192 + w * 1024);
  };

  // hoisted lane-invariant LDS read offsets: byte = r*128 + ((x*64+lh*16)^((lg&7)<<4)),
  // r = frag*16+lg  =>  frag*2048 folds into the ds_read immediate.
  const int swz = (lg & 7) << 4;
  const int off0 = lg * 128 + ((lh * 16) ^ swz);
  const int off1 = lg * 128 + (((64 + lh * 16)) ^ swz);

  const f32x4 zero = {0.f, 0.f, 0.f, 0.f};
  f32x4 o_[4][2];   // [df][qf] : O^T frag, row d = df*16+lh*4+i, col q = qf*16+lg
  float m_[2], lp_[2];
#pragma unroll
  for (int df = 0; df < 4; ++df)
#pragma unroll
    for (int qf = 0; qf < 2; ++qf) o_[df][qf] = zero;
  m_[0] = m_[1] = -1e30f;
  lp_[0] = lp_[1] = 0.f;

  const float C = 0.18033688f;   // log2(e)/sqrt(64)
  const float DT = 44.361f;      // 8/C -> P bounded by 2^8

  STAGE(0, 0);
  __syncthreads();
#pragma unroll 2
  for (int kt = 0; kt < 16; ++kt) {
    const int cur = kt & 1;
    const char* Kc = lds + cur * 8192;
    const char* Vc = lds + 16384 + cur * 8192;
    if (kt < 15) STAGE(cur ^ 1, kt + 1);

    // S^T[kv][q] : A = K rows (kv), B = Q cols (q)
    f32x4 st[4][2];
#pragma unroll
    for (int kvf = 0; kvf < 4; ++kvf)
#pragma unroll
      for (int mff = 0; mff < 2; ++mff) st[kvf][mff] = zero;
    __builtin_amdgcn_s_setprio(1);
#pragma unroll
    for (int dc = 0; dc < 2; ++dc)
#pragma unroll
      for (int kvf = 0; kvf < 4; ++kvf) {
        bf16x8 kf = *(const bf16x8*)(Kc + (dc ? off1 : off0) + kvf * 2048);
#pragma unroll
        for (int mff = 0; mff < 2; ++mff)
          st[kvf][mff] = __builtin_amdgcn_mfma_f32_16x16x32_bf16(kf, qfr[mff][dc], st[kvf][mff], 0, 0, 0);
      }
    __builtin_amdgcn_s_setprio(0);

    // row-max per q: lane-local tree, then xor16/32 across lh groups
    float pmax[2];
#pragma unroll
    for (int qf = 0; qf < 2; ++qf) {
      float ma[4];
#pragma unroll
      for (int i = 0; i < 4; ++i)
        ma[i] = fmaxf(fmaxf(st[0][qf][i], st[1][qf][i]),
                      fmaxf(st[2][qf][i], st[3][qf][i]));
      float t = fmaxf(fmaxf(ma[0], ma[1]), fmaxf(ma[2], ma[3]));
      t = fmaxf(t, __shfl_xor(t, 16));
      t = fmaxf(t, __shfl_xor(t, 32));
      pmax[qf] = t;
    }

    // defer-max: rescale only when a row grew past threshold (wave-uniform branch)
    int need = (pmax[0] - m_[0] > DT) || (pmax[1] - m_[1] > DT);
    if (__any(need)) {
#pragma unroll
      for (int qf = 0; qf < 2; ++qf) {
        float nm = fmaxf(m_[qf], pmax[qf]);
        float r = __builtin_amdgcn_exp2f((m_[qf] - nm) * C);
        m_[qf] = nm;
        lp_[qf] *= r;
#pragma unroll
        for (int df = 0; df < 4; ++df)
#pragma unroll
          for (int i = 0; i < 4; ++i) o_[df][qf][i] *= r;
      }
    }

    // P = exp2((s-m)*C), per-lane partial row-sum, native-cast pack to bf16
    bf16x4 pb[4][2];
#pragma unroll
    for (int qf = 0; qf < 2; ++qf) {
      float rs = 0.f;
      float mc = -m_[qf] * C;
#pragma unroll
      for (int kvf = 0; kvf < 4; ++kvf) {
#pragma unroll
        for (int i = 0; i < 4; ++i) {
          float p = __builtin_amdgcn_exp2f(fmaf(st[kvf][qf][i], C, mc));
          pb[kvf][qf][i] = (__bf16)p;
          rs += p;
        }
      }
      lp_[qf] += rs;   // cross-lane reduce deferred to epilogue
    }

    // O^T += V^T P : K32 MFMA; b128 V read = A-frag, concat(pb[2p],pb[2p+1]) = B-frag
    __builtin_amdgcn_s_setprio(1);
#pragma unroll
    for (int p = 0; p < 2; ++p) {
      union { bf16x4 h[2]; bf16x8 v; } pc[2];
#pragma unroll
      for (int qf = 0; qf < 2; ++qf) {
        pc[qf].h[0] = pb[2 * p][qf];
        pc[qf].h[1] = pb[2 * p + 1][qf];
      }
#pragma unroll
      for (int df = 0; df < 4; ++df) {
        bf16x8 vv = *(const bf16x8*)(Vc + (p ? off1 : off0) + df * 2048);
#pragma unroll
        for (int qf = 0; qf < 2; ++qf)
          o_[df][qf] = __builtin_amdgcn_mfma_f32_16x16x32_bf16(vv, pc[qf].v, o_[df][qf], 0, 0, 0);
      }
    }
    __builtin_amdgcn_s_setprio(0);

    // explicit drain of outstanding global_load_lds before the barrier
    asm volatile("s_waitcnt vmcnt(0)" ::: "memory");
    __syncthreads();
  }

  // final l reduce + normalize + store (i-dim = consecutive d -> 8B stores)
#pragma unroll
  for (int qf = 0; qf < 2; ++qf) {
    float ls = lp_[qf];
    ls += __shfl_xor(ls, 16);
    ls += __shfl_xor(ls, 32);
    float inv = 1.f / ls;
    size_t qrow = (size_t)(qrow0 + qf * 16 + lg) * 1024 + h * 64;
#pragma unroll
    for (int df = 0; df < 4; ++df) {
      bf16x4 ov;
#pragma unroll
      for (int i = 0; i < 4; ++i) ov[i] = (__bf16)(o_[df][qf][i] * inv);
      *(bf16x4*)(Ob + qrow + df * 16 + lh * 4) = ov;
    }
  }
}

extern "C" void kernel_launch(void* const* d_in, const int* in_sizes, int n_in,
                              void* d_out, int out_size, void* d_ws, size_t ws_size,
                              hipStream_t stream) {
  const float* x     = (const float*)d_in[0];
  const float* ctx   = (const float*)d_in[1];
  const float* Wq    = (const float*)d_in[2];
  const float* Wkv   = (const float*)d_in[3];
  const float* Wproj = (const float*)d_in[4];
  const float* qg    = (const float*)d_in[5];
  const float* kg    = (const float*)d_in[6];
  float* out = (float*)d_out;

  // B=4 L=4096 Lc=1024 D=1024 CTX=1024 H=16 hd=64
  char* ws = (char*)d_ws;
  __bf16* xb   = (__bf16*)(ws);                        // 32MB; reused as Ob
  __bf16* cb   = (__bf16*)(ws + (size_t)32 * 1048576); // 8MB
  __bf16* Wqt  = (__bf16*)(ws + (size_t)40 * 1048576); // 2MB
  __bf16* Wkvt = (__bf16*)(ws + (size_t)42 * 1048576); // 4MB
  __bf16* Wpt  = (__bf16*)(ws + (size_t)46 * 1048576); // 2MB
  __bf16* Qb   = (__bf16*)(ws + (size_t)48 * 1048576); // 32MB
  __bf16* Kb   = (__bf16*)(ws + (size_t)80 * 1048576); // 8MB  [4096,1024]
  __bf16* Vt   = (__bf16*)(ws + (size_t)88 * 1048576); // 8MB  [b,h,d,kvp]
  __bf16* Ob   = xb;  // xb is dead after the Q GEMM

  conv_bf16_kernel<<<16384, 256, 0, stream>>>(x, xb, 4194304);
  conv_bf16_kernel<<<4096, 256, 0, stream>>>(ctx, cb, 1048576);
  tconv_kernel<<<dim3(32, 32), dim3(32, 8), 0, stream>>>(Wq, Wqt, 1024, 1024);
  tconv_kernel<<<dim3(64, 32), dim3(32, 8), 0, stream>>>(Wkv, Wkvt, 1024, 2048);
  tconv_kernel<<<dim3(32, 32), dim3(32, 8), 0, stream>>>(Wproj, Wpt, 1024, 1024);

  gemm_kernel<1, 0><<<dim3(8, 128), 256, 0, stream>>>(xb, Wqt, Qb, nullptr, 16384, 1024, 1024, qg);
  gemm_kernel<2, 0><<<dim3(16, 32), 256, 0, stream>>>(cb, Wkvt, Kb, Vt, 4096, 2048, 1024, kg);
  flash_kernel<<<1024, 512, 0, stream>>>(Qb, Kb, Vt, Ob);
  gemm_kernel<0, 1><<<dim3(8, 128), 256, 0, stream>>>(Ob, Wpt, out, nullptr, 16384, 1024, 1024, nullptr);
}

// Round 8
// 257.978 us; speedup vs baseline: 2.0604x; 1.0770x over previous
//
#include <hip/hip_runtime.h>

typedef __bf16 bf16x8 __attribute__((ext_vector_type(8)));
typedef __bf16 bf16x4 __attribute__((ext_vector_type(4)));
typedef float f32x4 __attribute__((ext_vector_type(4)));

__device__ __forceinline__ void gl_lds16(const void* g, void* l) {
  __builtin_amdgcn_global_load_lds(
      (const __attribute__((address_space(1))) unsigned int*)g,
      (__attribute__((address_space(3))) unsigned int*)l, 16, 0, 0);
}

// ---------------- f32 -> bf16 convert (vectorized, native casts) ----------------
__global__ __launch_bounds__(256) void conv_bf16_kernel(
    const float* __restrict__ in, __bf16* __restrict__ out, int n4) {
  int i = blockIdx.x * 256 + threadIdx.x;
  if (i < n4) {
    float4 v = ((const float4*)in)[i];
    bf16x4 o;
    o[0] = (__bf16)v.x; o[1] = (__bf16)v.y; o[2] = (__bf16)v.z; o[3] = (__bf16)v.w;
    *(bf16x4*)(out + (size_t)i * 4) = o;
  }
}

// ---------------- f32 [R][C] -> bf16 transposed [C][R] ----------------
__global__ __launch_bounds__(256) void tconv_kernel(
    const float* __restrict__ W, __bf16* __restrict__ Wt, int R, int C) {
  __shared__ float t[32][33];
  int c0 = blockIdx.x * 32, r0 = blockIdx.y * 32;
  int tx = threadIdx.x, ty = threadIdx.y;
#pragma unroll
  for (int i = 0; i < 4; ++i)
    t[ty + i * 8][tx] = W[(size_t)(r0 + ty + i * 8) * C + c0 + tx];
  __syncthreads();
#pragma unroll
  for (int i = 0; i < 4; ++i)
    Wt[(size_t)(c0 + ty + i * 8) * R + r0 + tx] = (__bf16)t[tx][ty + i * 8];
}

// ---------------- bf16 GEMM (2-phase dbuf): C[M,N] = A[M,K] * Bt[N,K]^T ----------------
// NORM==1: per-64-col RMSNorm (q), plain write to Cout [M,N] bf16
// NORM==2: KV mode. cols<1024: RMSNorm + write K to Cout as [M,1024] bf16 (compact).
//          cols>=1024: write V transposed+kv-permuted to Cout2 = Vt[b,h,d,kvp].
// NORM==0: plain; OUTF32 selects f32 output.
template <int NORM, int OUTF32>
__global__ __launch_bounds__(256) void gemm_kernel(
    const __bf16* __restrict__ A, const __bf16* __restrict__ Bt,
    void* __restrict__ Cout, void* __restrict__ Cout2,
    int M, int N, int K, const float* __restrict__ gamma) {
  __shared__ alignas(16) __bf16 Alds[2][128 * 32];
  __shared__ alignas(16) __bf16 Blds[2][128 * 32];
  const int tid = threadIdx.x;
  const int w = tid >> 6, l = tid & 63;
  const int lg = l & 15, lh = l >> 4;
  const int wr = w >> 1, wc = w & 1;

  // XCD-bijective swizzle: same-XCD blocks walk bcol fastest within a brow-slab,
  // so each XCD keeps its B-panels L2-resident and streams an A-slab.
  const int nbx = gridDim.x;
  const int lid = blockIdx.y * nbx + blockIdx.x;
  const int cpx = (nbx * gridDim.y) >> 3;
  const int swz = (lid & 7) * cpx + (lid >> 3);
  const int brow = (swz / nbx) * 128, bcol = (swz % nbx) * 128;

  const f32x4 zero = {0.f, 0.f, 0.f, 0.f};
  f32x4 acc[4][4];
#pragma unroll
  for (int m = 0; m < 4; ++m)
#pragma unroll
    for (int n = 0; n < 4; ++n) acc[m][n] = zero;

  auto STAGE = [&](int buf, int k0) {
#pragma unroll
    for (int j = 0; j < 2; ++j) {
      int c = j * 256 + w * 64 + l;
      gl_lds16(A + (size_t)(brow + (c >> 2)) * K + k0 + (c & 3) * 8,
               (char*)Alds[buf] + (j * 256 + w * 64) * 16);
      gl_lds16(Bt + (size_t)(bcol + (c >> 2)) * K + k0 + (c & 3) * 8,
               (char*)Blds[buf] + (j * 256 + w * 64) * 16);
    }
  };

  STAGE(0, 0);
  __syncthreads();
  for (int k0 = 0; k0 < K; k0 += 32) {
    int cur = (k0 >> 5) & 1;
    if (k0 + 32 < K) STAGE(cur ^ 1, k0 + 32);
    bf16x8 af[4], bfr[4];
#pragma unroll
    for (int m = 0; m < 4; ++m)
      af[m] = *(const bf16x8*)(Alds[cur] + (wr * 64 + m * 16 + lg) * 32 + lh * 8);
#pragma unroll
    for (int n = 0; n < 4; ++n)
      bfr[n] = *(const bf16x8*)(Blds[cur] + (wc * 64 + n * 16 + lg) * 32 + lh * 8);
#pragma unroll
    for (int m = 0; m < 4; ++m)
#pragma unroll
      for (int n = 0; n < 4; ++n)
        acc[m][n] = __builtin_amdgcn_mfma_f32_16x16x32_bf16(af[m], bfr[n], acc[m][n], 0, 0, 0);
    __syncthreads();
  }

  const int col64 = bcol + wc * 64;
  if (NORM == 1 || (NORM == 2 && col64 < 1024)) {
    float gm[4];
#pragma unroll
    for (int n = 0; n < 4; ++n) gm[n] = gamma[n * 16 + lg];
#pragma unroll
    for (int m = 0; m < 4; ++m) {
#pragma unroll
      for (int i = 0; i < 4; ++i) {
        float ss = 0.f;
#pragma unroll
        for (int n = 0; n < 4; ++n) ss += acc[m][n][i] * acc[m][n][i];
        ss += __shfl_xor(ss, 1);
        ss += __shfl_xor(ss, 2);
        ss += __shfl_xor(ss, 4);
        ss += __shfl_xor(ss, 8);
        float inv = rsqrtf(ss * (1.0f / 64.0f) + 1e-6f);
#pragma unroll
        for (int n = 0; n < 4; ++n) acc[m][n][i] *= inv * gm[n];
      }
    }
  }

  if (NORM == 2) {
    if (col64 < 1024) {
#pragma unroll
      for (int m = 0; m < 4; ++m)
#pragma unroll
        for (int n = 0; n < 4; ++n)
#pragma unroll
          for (int i = 0; i < 4; ++i) {
            size_t idx = (size_t)(brow + wr * 64 + m * 16 + lh * 4 + i) * 1024 +
                         col64 + n * 16 + lg;
            ((__bf16*)Cout)[idx] = (__bf16)acc[m][n][i];
          }
    } else {
      // V half -> Vt[b,h,d,kvp]: i-dim = 4 consecutive kv = contiguous after permute
#pragma unroll
      for (int m = 0; m < 4; ++m) {
        int row = brow + wr * 64 + m * 16 + lh * 4;   // global ctx row = b*1024 + kv
        int bb = row >> 10, kv0 = row & 1023;
        int g = kv0 & 31;
        int pos = (kv0 & ~31) + ((g & 15) >> 2) * 8 + (g >> 4) * 4;
#pragma unroll
        for (int n = 0; n < 4; ++n) {
          int col = col64 + n * 16 + lg - 1024;       // = h*64 + d
          bf16x4 v;
#pragma unroll
          for (int i = 0; i < 4; ++i) v[i] = (__bf16)acc[m][n][i];
          *(bf16x4*)((__bf16*)Cout2 + ((size_t)(bb * 1024 + col)) * 1024 + pos) = v;
        }
      }
    }
    return;
  }

#pragma unroll
  for (int m = 0; m < 4; ++m)
#pragma unroll
    for (int n = 0; n < 4; ++n)
#pragma unroll
      for (int i = 0; i < 4; ++i) {
        size_t idx = (size_t)(brow + wr * 64 + m * 16 + lh * 4 + i) * N +
                     bcol + wc * 64 + n * 16 + lg;
        if (OUTF32) ((float*)Cout)[idx] = acc[m][n][i];
        else ((__bf16*)Cout)[idx] = (__bf16)acc[m][n][i];
      }
}

// ---------------- flash attention v8: 4-buffer LDS, 2 KV-tiles per barrier ----------------
__global__ __launch_bounds__(512) void flash_kernel(
    const __bf16* __restrict__ Qb, const __bf16* __restrict__ Kb,
    const __bf16* __restrict__ Vt, __bf16* __restrict__ Ob) {
  // XCD-aware bijective swizzle: 1024 blocks, 8 XCDs, 128 per XCD.
  const int orig = blockIdx.x;
  const int wgid = (orig & 7) * 128 + (orig >> 3);
  const int qt = wgid & 15, h = (wgid >> 4) & 15, b = wgid >> 8;
  const int tid = threadIdx.x;
  const int w = tid >> 6, l = tid & 63, lg = l & 15, lh = l >> 4;
  // K buf n at n*8192 ; V buf n at 32768 + n*8192  (n = 0..3)
  __shared__ alignas(16) char lds[65536];

  const int qrow0 = b * 4096 + qt * 256 + w * 32;
  bf16x8 qfr[2][2];
#pragma unroll
  for (int mff = 0; mff < 2; ++mff)
#pragma unroll
    for (int dc = 0; dc < 2; ++dc)
      qfr[mff][dc] = *(const bf16x8*)(Qb + (size_t)(qrow0 + mff * 16 + lg) * 1024 +
                                      h * 64 + dc * 32 + lh * 8);

  const char* Kg = (const char*)Kb + (size_t)b * 2097152 + h * 128;  // row stride 2048B
  const char* Vg = (const char*)Vt + (size_t)(b * 16 + h) * 64 * 2048;

  // staging: per-thread 1 K-load + 1 V-load per tile; linear LDS dest, pre-swizzled src
  const int o16 = tid * 16;
  const int op = o16 ^ (((o16 >> 7) & 7) << 4);
  const int srow = op >> 7, scb = op & 127;

  auto STAGE = [&](int buf, int kt) {
    gl_lds16(Kg + (size_t)(kt * 64 + srow) * 2048 + scb, lds + buf * 8192 + w * 1024);
    gl_lds16(Vg + (size_t)srow * 2048 + kt * 128 + scb, lds + 32768 + buf * 8192 + w * 1024);
  };

  // hoisted lane-invariant LDS read offsets: byte = r*128 + ((x*64+lh*16)^((lg&7)<<4)),
  // r = frag*16+lg  =>  frag*2048 folds into the ds_read immediate.
  const int swzl = (lg & 7) << 4;
  const int off0 = lg * 128 + ((lh * 16) ^ swzl);
  const int off1 = lg * 128 + ((64 + lh * 16) ^ swzl);

  const f32x4 zero = {0.f, 0.f, 0.f, 0.f};
  f32x4 o_[4][2];   // [df][qf] : O^T frag, row d = df*16+lh*4+i, col q = qf*16+lg
  float m_[2], lp_[2];
#pragma unroll
  for (int df = 0; df < 4; ++df)
#pragma unroll
    for (int qf = 0; qf < 2; ++qf) o_[df][qf] = zero;
  m_[0] = m_[1] = -1e30f;
  lp_[0] = lp_[1] = 0.f;

  const float C = 0.18033688f;   // log2(e)/sqrt(64)
  const float DT = 44.361f;      // 8/C -> P bounded by 2^8

  auto COMPUTE = [&](const char* Kc, const char* Vc) {
    // S^T[kv][q] : A = K rows (kv), B = Q cols (q)
    f32x4 st[4][2];
#pragma unroll
    for (int kvf = 0; kvf < 4; ++kvf)
#pragma unroll
      for (int mff = 0; mff < 2; ++mff) st[kvf][mff] = zero;
    __builtin_amdgcn_s_setprio(1);
#pragma unroll
    for (int dc = 0; dc < 2; ++dc)
#pragma unroll
      for (int kvf = 0; kvf < 4; ++kvf) {
        bf16x8 kf = *(const bf16x8*)(Kc + (dc ? off1 : off0) + kvf * 2048);
#pragma unroll
        for (int mff = 0; mff < 2; ++mff)
          st[kvf][mff] = __builtin_amdgcn_mfma_f32_16x16x32_bf16(kf, qfr[mff][dc], st[kvf][mff], 0, 0, 0);
      }
    __builtin_amdgcn_s_setprio(0);

    // row-max per q: lane-local tree, then xor16/32 across lh groups
    float pmax[2];
#pragma unroll
    for (int qf = 0; qf < 2; ++qf) {
      float ma[4];
#pragma unroll
      for (int i = 0; i < 4; ++i)
        ma[i] = fmaxf(fmaxf(st[0][qf][i], st[1][qf][i]),
                      fmaxf(st[2][qf][i], st[3][qf][i]));
      float t = fmaxf(fmaxf(ma[0], ma[1]), fmaxf(ma[2], ma[3]));
      t = fmaxf(t, __shfl_xor(t, 16));
      t = fmaxf(t, __shfl_xor(t, 32));
      pmax[qf] = t;
    }

    // defer-max: rescale only when a row grew past threshold (wave-uniform branch)
    int need = (pmax[0] - m_[0] > DT) || (pmax[1] - m_[1] > DT);
    if (__any(need)) {
#pragma unroll
      for (int qf = 0; qf < 2; ++qf) {
        float nm = fmaxf(m_[qf], pmax[qf]);
        float r = __builtin_amdgcn_exp2f((m_[qf] - nm) * C);
        m_[qf] = nm;
        lp_[qf] *= r;
#pragma unroll
        for (int df = 0; df < 4; ++df)
#pragma unroll
          for (int i = 0; i < 4; ++i) o_[df][qf][i] *= r;
      }
    }

    // P = exp2((s-m)*C), per-lane partial row-sum, native-cast pack to bf16
    bf16x4 pb[4][2];
#pragma unroll
    for (int qf = 0; qf < 2; ++qf) {
      float rs = 0.f;
      float mc = -m_[qf] * C;
#pragma unroll
      for (int kvf = 0; kvf < 4; ++kvf) {
#pragma unroll
        for (int i = 0; i < 4; ++i) {
          float p = __builtin_amdgcn_exp2f(fmaf(st[kvf][qf][i], C, mc));
          pb[kvf][qf][i] = (__bf16)p;
          rs += p;
        }
      }
      lp_[qf] += rs;   // cross-lane reduce deferred to epilogue
    }

    // O^T += V^T P : K32 MFMA; b128 V read = A-frag, concat(pb[2p],pb[2p+1]) = B-frag
    __builtin_amdgcn_s_setprio(1);
#pragma unroll
    for (int p = 0; p < 2; ++p) {
      union { bf16x4 hv[2]; bf16x8 v; } pc[2];
#pragma unroll
      for (int qf = 0; qf < 2; ++qf) {
        pc[qf].hv[0] = pb[2 * p][qf];
        pc[qf].hv[1] = pb[2 * p + 1][qf];
      }
#pragma unroll
      for (int df = 0; df < 4; ++df) {
        bf16x8 vv = *(const bf16x8*)(Vc + (p ? off1 : off0) + df * 2048);
#pragma unroll
        for (int qf = 0; qf < 2; ++qf)
          o_[df][qf] = __builtin_amdgcn_mfma_f32_16x16x32_bf16(vv, pc[qf].v, o_[df][qf], 0, 0, 0);
      }
    }
    __builtin_amdgcn_s_setprio(0);
  };

  STAGE(0, 0);
  STAGE(1, 1);
  __syncthreads();
#pragma unroll 2
  for (int it = 0; it < 8; ++it) {
    const int pb_ = (it & 1) * 2;           // current buffer pair {pb_, pb_+1}
    if (it < 7) {                           // prefetch next pair (read-done via prev barrier)
      STAGE(pb_ ^ 2, 2 * it + 2);
      STAGE((pb_ ^ 2) + 1, 2 * it + 3);
    }
    COMPUTE(lds + pb_ * 8192, lds + 32768 + pb_ * 8192);
    COMPUTE(lds + (pb_ + 1) * 8192, lds + 32768 + (pb_ + 1) * 8192);
    // drain this iteration's prefetch before the single barrier per 2 tiles
    asm volatile("s_waitcnt vmcnt(0)" ::: "memory");
    __syncthreads();
  }

  // final l reduce + normalize + store (i-dim = consecutive d -> 8B stores)
#pragma unroll
  for (int qf = 0; qf < 2; ++qf) {
    float ls = lp_[qf];
    ls += __shfl_xor(ls, 16);
    ls += __shfl_xor(ls, 32);
    float inv = 1.f / ls;
    size_t qrow = (size_t)(qrow0 + qf * 16 + lg) * 1024 + h * 64;
#pragma unroll
    for (int df = 0; df < 4; ++df) {
      bf16x4 ov;
#pragma unroll
      for (int i = 0; i < 4; ++i) ov[i] = (__bf16)(o_[df][qf][i] * inv);
      *(bf16x4*)(Ob + qrow + df * 16 + lh * 4) = ov;
    }
  }
}

extern "C" void kernel_launch(void* const* d_in, const int* in_sizes, int n_in,
                              void* d_out, int out_size, void* d_ws, size_t ws_size,
                              hipStream_t stream) {
  const float* x     = (const float*)d_in[0];
  const float* ctx   = (const float*)d_in[1];
  const float* Wq    = (const float*)d_in[2];
  const float* Wkv   = (const float*)d_in[3];
  const float* Wproj = (const float*)d_in[4];
  const float* qg    = (const float*)d_in[5];
  const float* kg    = (const float*)d_in[6];
  float* out = (float*)d_out;

  // B=4 L=4096 Lc=1024 D=1024 CTX=1024 H=16 hd=64
  char* ws = (char*)d_ws;
  __bf16* xb   = (__bf16*)(ws);                        // 32MB; reused as Ob
  __bf16* cb   = (__bf16*)(ws + (size_t)32 * 1048576); // 8MB
  __bf16* Wqt  = (__bf16*)(ws + (size_t)40 * 1048576); // 2MB
  __bf16* Wkvt = (__bf16*)(ws + (size_t)42 * 1048576); // 4MB
  __bf16* Wpt  = (__bf16*)(ws + (size_t)46 * 1048576); // 2MB
  __bf16* Qb   = (__bf16*)(ws + (size_t)48 * 1048576); // 32MB
  __bf16* Kb   = (__bf16*)(ws + (size_t)80 * 1048576); // 8MB  [4096,1024]
  __bf16* Vt   = (__bf16*)(ws + (size_t)88 * 1048576); // 8MB  [b,h,d,kvp]
  __bf16* Ob   = xb;  // xb is dead after the Q GEMM

  conv_bf16_kernel<<<16384, 256, 0, stream>>>(x, xb, 4194304);
  conv_bf16_kernel<<<4096, 256, 0, stream>>>(ctx, cb, 1048576);
  tconv_kernel<<<dim3(32, 32), dim3(32, 8), 0, stream>>>(Wq, Wqt, 1024, 1024);
  tconv_kernel<<<dim3(64, 32), dim3(32, 8), 0, stream>>>(Wkv, Wkvt, 1024, 2048);
  tconv_kernel<<<dim3(32, 32), dim3(32, 8), 0, stream>>>(Wproj, Wpt, 1024, 1024);

  gemm_kernel<1, 0><<<dim3(8, 128), 256, 0, stream>>>(xb, Wqt, Qb, nullptr, 16384, 1024, 1024, qg);
  gemm_kernel<2, 0><<<dim3(16, 32), 256, 0, stream>>>(cb, Wkvt, Kb, Vt, 4096, 2048, 1024, kg);
  flash_kernel<<<1024, 512, 0, stream>>>(Qb, Kb, Vt, Ob);
  gemm_kernel<0, 1><<<dim3(8, 128), 256, 0, stream>>>(Ob, Wpt, out, nullptr, 16384, 1024, 1024, nullptr);
}